// Round 16
// baseline (120.093 us; speedup 1.0000x reference)
//
#include <hip/hip_runtime.h>
#include <hip/hip_bf16.h>

typedef __bf16 bf16x8v __attribute__((ext_vector_type(8)));
typedef float f32x4 __attribute__((ext_vector_type(4)));

#define GLD16(gp, loff)                                                     \
  __builtin_amdgcn_global_load_lds(                                         \
      (const __attribute__((address_space(1))) void*)(gp),                  \
      (__attribute__((address_space(3))) void*)(smem + (loff)), 16, 0, 0)

// ---------------------------------------------------------------------------
// Pipeline:
//  xp   : [b][q:11^4][64] padded L1 out (bf16, zero halo), via l1_fused MFMA
//         (in-LDS im2col build -> MFMA -> halo scatter; no Aim round-trip).
//  part : 2 x [26244][128] bf16 L2 partials (K-split halves)
//  a2   : [26244][128] bf16;  a4 : [26244][256] bf16;  a5 : [b*625][128] bf16
//  L2: r13-proven grid(206,2) K-split, 4 waves 2Mx2N (64x64), 2x32KB dbuf.
// ---------------------------------------------------------------------------

__global__ __launch_bounds__(256) void prep_fused(
    const float* __restrict__ w1r, const float* __restrict__ w1i,
    const float* __restrict__ w2r, const float* __restrict__ w2i,
    const float* __restrict__ w3r, const float* __restrict__ w3i,
    const float* __restrict__ w4r, const float* __restrict__ w4i,
    const float* __restrict__ w5r, const float* __restrict__ w5i,
    __hip_bfloat16* __restrict__ w1b, __hip_bfloat16* __restrict__ wt2b,
    __hip_bfloat16* __restrict__ w3b, __hip_bfloat16* __restrict__ w4b,
    __hip_bfloat16* __restrict__ w5b, uint4* __restrict__ xpz) {
  const int bx = blockIdx.x;
  const int tid = threadIdx.x;
  auto pack11 = [](const float* wr, const float* wi, __hip_bfloat16* dst,
                   int Cout, int Cin, int idx) {
    int k2 = 2 * Cin;
    int k = idx % k2, n = idx / k2;
    int ci = (k < Cin) ? k : k - Cin;
    int co = (n < Cout) ? n : n - Cout;
    int widx = co * Cin + ci;
    float v;
    if (n < Cout) v = (k < Cin) ? wr[widx] : -wi[widx];
    else          v = (k < Cin) ? wi[widx] :  wr[widx];
    dst[idx] = __float2bfloat16(v);
  };
  if (bx < 1831) {                       // zero xp (incl. halo), 7.5 MB
    int i = bx * 256 + tid;
    if (i < 468512) xpz[i] = make_uint4(0, 0, 0, 0);
  } else if (bx < 4423) {                // wt2b taps 0..80: B[t][n:128][k:64]
    int idx = (bx - 1831) * 256 + tid;
    int k = idx & 63, n = (idx >> 6) & 127, t = idx >> 13;
    int ci = k & 31, kin_i = k >> 5;
    int co = n & 63, out_i = n >> 6;
    int widx = (co * 32 + ci) * 81 + t;
    float v;
    if (out_i == 0) v = (kin_i == 0) ? w2r[widx] : -w2i[widx];
    else            v = (kin_i == 0) ? w2i[widx] :  w2r[widx];
    wt2b[idx] = __float2bfloat16(v);
  } else if (bx < 4487) {                // w1b: [n:64][k:256]
    int idx = (bx - 4423) * 256 + tid;
    int n = idx >> 8, k = idx & 255;
    int t = k >> 1, c = k & 1, co = n & 31;
    float v = 0.f;
    if (t < 81) {
      if (n < 32) v = c ? -w1i[co * 81 + t] : w1r[co * 81 + t];
      else        v = c ?  w1r[co * 81 + t] : w1i[co * 81 + t];
    }
    w1b[idx] = __float2bfloat16(v);
  } else if (bx < 4615) {
    pack11(w3r, w3i, w3b, 128, 64, (bx - 4487) * 256 + tid);
  } else if (bx < 4871) {
    pack11(w4r, w4i, w4b, 128, 128, (bx - 4615) * 256 + tid);
  } else {
    pack11(w5r, w5i, w5b, 64, 128, (bx - 4871) * 256 + tid);
  }
}

// ---- L1 fused: in-LDS im2col (write-swizzled) -> MFMA -> scatter into xp. --
// M=26244, N=64, K=256 (162 real). 8 waves 4Mx2N, wave tile 32x32.
__global__ __launch_bounds__(512) void l1_fused(
    const float* __restrict__ xr, const float* __restrict__ xi,
    const __hip_bfloat16* __restrict__ Bm, const float* __restrict__ br,
    const float* __restrict__ bi, __hip_bfloat16* __restrict__ xp) {
  __shared__ __align__(128) char smem[65536];  // 128 rows x 512 B
  const int tid = threadIdx.x, l = tid & 63, w = tid >> 6;
  const int wm = w & 3, wn = w >> 2;  // 4M x 2N
  const int p0 = blockIdx.x * 128;

  // ---- build A tile: 4 threads/row, 32 u32 slots each (tap -> bf16x2) -----
  {
    int row = tid >> 2;
    int s0 = (tid & 3) * 32;
    int m = p0 + row;
    if (m > 26243) m = 26243;
    int b = m / 6561, p = m % 6561;
    int d1 = p / 729, r = p % 729;
    int d2 = r / 81;
    r %= 81;
    int d3 = r / 9, d4 = r % 9;
    const int base = b * 160000 + d1 * 16000 + d2 * 800 + d3 * 40 + d4 * 2;
    uint* lrow = (uint*)smem + row * 128;
    const int xv = (row & 7) << 2;  // u32-index XOR == byte XOR ((row&7)<<4)
#pragma unroll
    for (int j = 0; j < 32; ++j) {
      int s = s0 + j;
      uint val = 0u;
      if (s < 81) {
        int j1 = s / 27, j2 = (s / 9) % 3, j3 = (s / 3) % 3, j4 = s % 3;
        int xo = base + j1 * 8000 + j2 * 400 + j3 * 20 + j4;
        __hip_bfloat16 h2[2] = {__float2bfloat16(xr[xo]),
                                __float2bfloat16(xi[xo])};
        val = *(const uint*)h2;
      }
      lrow[s ^ xv] = val;
    }
  }
  __syncthreads();

  const int l15 = l & 15;
  const int klo = (l >> 4) << 4;
  const int sx = (l & 7) << 4;
  const int arow0 = (wm * 32 + l15) * 512;
  const char* bb = (const char*)Bm + (size_t)(wn * 32 + l15) * 512 + klo;

  f32x4 acc[2][2];
#pragma unroll
  for (int mi = 0; mi < 2; ++mi)
#pragma unroll
    for (int ni = 0; ni < 2; ++ni) acc[mi][ni] = (f32x4){0.f, 0.f, 0.f, 0.f};

#pragma unroll
  for (int kh = 0; kh < 8; ++kh) {
    bf16x8v bfr[2];
#pragma unroll
    for (int ni = 0; ni < 2; ++ni)
      bfr[ni] = *(const bf16x8v*)(bb + ni * 16 * 512 + kh * 64);
    const int kx = ((kh << 6) + klo) ^ sx;
    bf16x8v af[2];
#pragma unroll
    for (int mi = 0; mi < 2; ++mi)
      af[mi] = *(const bf16x8v*)(smem + arow0 + mi * 8192 + kx);
#pragma unroll
    for (int mi = 0; mi < 2; ++mi)
#pragma unroll
      for (int ni = 0; ni < 2; ++ni)
        acc[mi][ni] = __builtin_amdgcn_mfma_f32_16x16x32_bf16(
            af[mi], bfr[ni], acc[mi][ni], 0, 0, 0);
  }

  const int prow = p0 + wm * 32 + ((l >> 4) << 2);
  const int col0 = wn * 32 + l15;
#pragma unroll
  for (int ni = 0; ni < 2; ++ni) {
    int cn = col0 + ni * 16;
    float bias = (cn < 32) ? br[cn] : bi[cn - 32];
#pragma unroll
    for (int mi = 0; mi < 2; ++mi)
#pragma unroll
      for (int j = 0; j < 4; ++j) {
        int m = prow + mi * 16 + j;
        if (m < 26244) {
          int b = m / 6561, p = m % 6561;
          int d1 = p / 729, r = p % 729;
          int d2 = r / 81;
          r %= 81;
          int d3 = r / 9, d4 = r % 9;
          int q = (((d1 + 1) * 11 + (d2 + 1)) * 11 + (d3 + 1)) * 11 + (d4 + 1);
          xp[((size_t)(b * 14641 + q)) * 64 + cn] =
              __float2bfloat16(fmaxf(acc[mi][ni][j] + bias, 0.f));
        }
      }
  }
}

// ---- Layer 2: r13-proven. K-split grid (206,2); 4 waves 2Mx2N (64x64);
//      BK=64; 2x32KB buffers; bf16 partial store. ---------------------------
__global__ __launch_bounds__(256) void cconv2_ksplit(
    const __hip_bfloat16* __restrict__ xp, const __hip_bfloat16* __restrict__ wb,
    __hip_bfloat16* __restrict__ part) {
  __shared__ __align__(128) char smem[65536];  // 2 x (A 16KB | B 16KB)
  const int tid = threadIdx.x;
  const int l = tid & 63, w = tid >> 6;        // 4 waves
  const int wm = w & 1, wn = w >> 1;           // 2M x 2N, wave tile 64x64
  const int m0 = blockIdx.x * 128;
  const int ky = blockIdx.y;                   // K-half: taps [0,41) / [41,81)

  const int swz = ((l & 7) ^ (l >> 3)) << 4;
  const char* xpB = (const char*)xp;
  const char* wB = (const char*)wb;
  int q00[4], rbB[4];
#pragma unroll
  for (int c = 0; c < 4; ++c) {
    int row = w * 32 + c * 8 + (l >> 3);
    int m = m0 + row;
    if (m > 26243) m = 26243;
    int b = m / 6561, p = m % 6561;
    int d1 = p / 729, r = p % 729;
    int d2 = r / 81;
    r %= 81;
    int d3 = r / 9, d4 = r % 9;
    q00[c] = b * 14641 + ((d1 * 11 + d2) * 11 + d3) * 11 + d4;
    rbB[c] = row * 128 + swz;
  }

  const int l15 = l & 15;
  const int klo = (l >> 4) << 4;
  const int sx = (l & 7) << 4;
  const int arow0 = (wm * 64 + l15) * 128;
  const int brow0 = 16384 + (wn * 64 + l15) * 128;

  f32x4 acc[4][4];
#pragma unroll
  for (int mi = 0; mi < 4; ++mi)
#pragma unroll
    for (int ni = 0; ni < 4; ++ni) acc[mi][ni] = (f32x4){0.f, 0.f, 0.f, 0.f};

  auto stage = [&](int t, int nb) {
    int j1 = t / 27, j2 = (t / 9) % 3, j3 = (t / 3) % 3, j4 = t % 3;
    int delta = ((j1 * 11 + j2) * 11 + j3) * 11 + j4;
#pragma unroll
    for (int c = 0; c < 4; ++c) {
      GLD16(xpB + (((size_t)(q00[c] + delta)) << 7) + swz,
            nb + w * 4096 + c * 1024);
      GLD16(wB + (((size_t)t) << 14) + rbB[c],
            nb + 16384 + w * 4096 + c * 1024);
    }
  };

  const int t0 = ky * 41;            // 0 or 41
  const int nt = 41 - ky;            // 41 or 40

  stage(t0, 0);

  for (int ti = 0; ti < nt; ++ti) {
    asm volatile("s_waitcnt vmcnt(0)" ::: "memory");
    __builtin_amdgcn_s_barrier();
    if (ti + 1 < nt) stage(t0 + ti + 1, ((ti + 1) & 1) * 32768);
    const char* sb = smem + (ti & 1) * 32768;
#pragma unroll
    for (int kh = 0; kh < 2; ++kh) {
      const int kx = ((kh << 6) + klo) ^ sx;
      bf16x8v af[4], bfr[4];
#pragma unroll
      for (int mi = 0; mi < 4; ++mi)
        af[mi] = *(const bf16x8v*)(sb + arow0 + mi * 2048 + kx);
#pragma unroll
      for (int ni = 0; ni < 4; ++ni)
        bfr[ni] = *(const bf16x8v*)(sb + brow0 + ni * 2048 + kx);
#pragma unroll
      for (int mi = 0; mi < 4; ++mi)
#pragma unroll
        for (int ni = 0; ni < 4; ++ni)
          acc[mi][ni] = __builtin_amdgcn_mfma_f32_16x16x32_bf16(
              af[mi], bfr[ni], acc[mi][ni], 0, 0, 0);
    }
  }

  __hip_bfloat16* pp = part + (size_t)ky * 3359232;
  const int prow = m0 + wm * 64 + ((l >> 4) << 2);
  const int col0 = wn * 64 + l15;
#pragma unroll
  for (int ni = 0; ni < 4; ++ni) {
    int cn = col0 + ni * 16;
#pragma unroll
    for (int mi = 0; mi < 4; ++mi)
#pragma unroll
      for (int j = 0; j < 4; ++j) {
        int m = prow + mi * 16 + j;
        if (m < 26244)
          pp[(size_t)m * 128 + cn] = __float2bfloat16(acc[mi][ni][j]);
      }
  }
}

// ---- reduce: a2 = bf16(relu(p0 + p1 + bias)) -------------------------------
__global__ __launch_bounds__(256) void reduce_a2(
    const uint2* __restrict__ p0, const uint2* __restrict__ p1,
    const float* __restrict__ br, const float* __restrict__ bi,
    __hip_bfloat16* __restrict__ a2) {
  int idx = blockIdx.x * 256 + threadIdx.x;
  if (idx >= 839808) return;  // 26244*128/4
  uint2 ua = p0[idx], ub = p1[idx];
  const __hip_bfloat16* a = (const __hip_bfloat16*)&ua;
  const __hip_bfloat16* b = (const __hip_bfloat16*)&ub;
  int cn0 = (idx << 2) & 127;
  __hip_bfloat16 o4[4];
#pragma unroll
  for (int e = 0; e < 4; ++e) {
    int cn = cn0 + e;
    float bias = (cn < 64) ? br[cn] : bi[cn - 64];
    float s = __bfloat162float(a[e]) + __bfloat162float(b[e]) + bias;
    o4[e] = __float2bfloat16(fmaxf(s, 0.f));
  }
  *(uint2*)(a2 + (size_t)idx * 4) = *(const uint2*)o4;
}

// ---- L3+L4 fused: a2-tile -> L3 -> relu a3-tile (LDS) -> L4 -> a4. ---------
__global__ __launch_bounds__(512) void gemm_fused34(
    const __hip_bfloat16* __restrict__ a2, const __hip_bfloat16* __restrict__ w3,
    const __hip_bfloat16* __restrict__ w4, const float* __restrict__ b3r,
    const float* __restrict__ b3i, const float* __restrict__ b4r,
    const float* __restrict__ b4i, __hip_bfloat16* __restrict__ a4) {
  __shared__ __align__(128) char smem[98304];  // a2 tile 32KB | a3 tile 64KB
  const int tid = threadIdx.x, l = tid & 63, w = tid >> 6;
  const int wm = w & 1, wn = w >> 1;  // 2M x 4N
  const int p0 = blockIdx.x * 128;

  {
    const char* aB = (const char*)a2;
#pragma unroll
    for (int g = 0; g < 4; ++g) {
      int W = (w * 4 + g) * 1024 + (l << 4);
      int row = W >> 8;
      int cb = W & 255;
      int m = p0 + row;
      if (m > 26243) m = 26243;
      GLD16(aB + (size_t)m * 256 + (cb ^ ((row & 7) << 4)), W);
    }
  }
  asm volatile("s_waitcnt vmcnt(0)" ::: "memory");
  __syncthreads();

  const int l15 = l & 15;
  const int klo = (l >> 4) << 4;
  const int sx = (l & 7) << 4;

  f32x4 acc[4][4];
#pragma unroll
  for (int mi = 0; mi < 4; ++mi)
#pragma unroll
    for (int ni = 0; ni < 4; ++ni) acc[mi][ni] = (f32x4){0.f, 0.f, 0.f, 0.f};

  {
    const int arow3 = (wm * 64 + l15) * 256;
    const char* b3b = (const char*)w3 + (size_t)(wn * 64 + l15) * 256 + klo;
#pragma unroll
    for (int kh = 0; kh < 4; ++kh) {
      const int kx = ((kh << 6) + klo) ^ sx;
      bf16x8v af[4], bfr[4];
#pragma unroll
      for (int mi = 0; mi < 4; ++mi)
        af[mi] = *(const bf16x8v*)(smem + arow3 + mi * 4096 + kx);
#pragma unroll
      for (int ni = 0; ni < 4; ++ni)
        bfr[ni] = *(const bf16x8v*)(b3b + ni * 4096 + kh * 64);
#pragma unroll
      for (int mi = 0; mi < 4; ++mi)
#pragma unroll
        for (int ni = 0; ni < 4; ++ni)
          acc[mi][ni] = __builtin_amdgcn_mfma_f32_16x16x32_bf16(
              af[mi], bfr[ni], acc[mi][ni], 0, 0, 0);
    }
  }

  __syncthreads();
  {
    const int lrow = wm * 64 + ((l >> 4) << 2);
    const int col0 = wn * 64 + l15;
#pragma unroll
    for (int ni = 0; ni < 4; ++ni) {
      int cn = col0 + ni * 16;
      float bias = (cn < 128) ? b3r[cn] : b3i[cn - 128];
#pragma unroll
      for (int mi = 0; mi < 4; ++mi) {
        int row = lrow + mi * 16;
#pragma unroll
        for (int j = 0; j < 4; ++j) {
          float v = fmaxf(acc[mi][ni][j] + bias, 0.f);
          int addr = (32768 + (row + j) * 512 + cn * 2) ^ (((row + j) & 7) << 4);
          *(__hip_bfloat16*)(smem + addr) = __float2bfloat16(v);
        }
      }
    }
  }
  __syncthreads();

#pragma unroll
  for (int mi = 0; mi < 4; ++mi)
#pragma unroll
    for (int ni = 0; ni < 4; ++ni) acc[mi][ni] = (f32x4){0.f, 0.f, 0.f, 0.f};
  {
    const int arow4 = 32768 + (wm * 64 + l15) * 512;
    const char* b4b = (const char*)w4 + (size_t)(wn * 64 + l15) * 512 + klo;
#pragma unroll
    for (int kh = 0; kh < 8; ++kh) {
      const int kx = ((kh << 6) + klo) ^ sx;
      bf16x8v af[4], bfr[4];
#pragma unroll
      for (int mi = 0; mi < 4; ++mi)
        af[mi] = *(const bf16x8v*)(smem + arow4 + mi * 8192 + kx);
#pragma unroll
      for (int ni = 0; ni < 4; ++ni)
        bfr[ni] = *(const bf16x8v*)(b4b + ni * 8192 + kh * 64);
#pragma unroll
      for (int mi = 0; mi < 4; ++mi)
#pragma unroll
        for (int ni = 0; ni < 4; ++ni)
          acc[mi][ni] = __builtin_amdgcn_mfma_f32_16x16x32_bf16(
              af[mi], bfr[ni], acc[mi][ni], 0, 0, 0);
    }
  }

  {
    const int prow = p0 + wm * 64 + ((l >> 4) << 2);
    const int col0 = wn * 64 + l15;
#pragma unroll
    for (int ni = 0; ni < 4; ++ni) {
      int cn = col0 + ni * 16;
      float bias = (cn < 128) ? b4r[cn] : b4i[cn - 128];
#pragma unroll
      for (int mi = 0; mi < 4; ++mi)
#pragma unroll
        for (int j = 0; j < 4; ++j) {
          int m = prow + mi * 16 + j;
          if (m < 26244)
            a4[(size_t)m * 256 + cn] =
                __float2bfloat16(fmaxf(acc[mi][ni][j] + bias, 0.f));
        }
    }
  }
}

// ---- L5 GEMM ---------------------------------------------------------------
template <int K, int S2>
__global__ __launch_bounds__(512) void gemm_bg(
    const __hip_bfloat16* __restrict__ A, const __hip_bfloat16* __restrict__ Bm,
    const float* __restrict__ br, const float* __restrict__ bi,
    __hip_bfloat16* __restrict__ C, int M, int N, int Cout) {
  constexpr int ROWB = 2 * K;
  constexpr int NKH = K / 32;
  constexpr int LG = (K == 128) ? 8 : 9;
  __shared__ __align__(128) char smem[128 * ROWB];
  const int tid = threadIdx.x, l = tid & 63, w = tid >> 6;
  const int wm = w & 1, wn = w >> 1;
  const int p0 = blockIdx.x * 128, n0 = blockIdx.y * 128;

  const char* aB = (const char*)A;
#pragma unroll
  for (int g = 0; g < NKH; ++g) {
    int W = (w * NKH + g) * 1024 + (l << 4);
    int row = W >> LG;
    int cb = W & (ROWB - 1);
    int m = p0 + row;
    if (m >= M) m = M - 1;
    int srcrow;
    if (S2) {
      int bb_ = m / 625, r = m % 625;
      int d1 = r / 125;
      r %= 125;
      int d2 = r / 25;
      r %= 25;
      int d3 = r / 5, d4 = r % 5;
      srcrow = bb_ * 6561 + d1 * 1458 + d2 * 162 + d3 * 18 + d4 * 2;
    } else {
      srcrow = m;
    }
    GLD16(aB + (size_t)srcrow * ROWB + (cb ^ ((row & 7) << 4)), W);
  }
  asm volatile("s_waitcnt vmcnt(0)" ::: "memory");
  __syncthreads();

  const int l15 = l & 15;
  const int klo = (l >> 4) << 4;
  const int sx = (l & 7) << 4;
  const int arow0 = (wm * 64 + l15) * ROWB;
  const char* bb = (const char*)Bm + (size_t)(n0 + wn * 32 + l15) * ROWB + klo;

  f32x4 acc[4][2];
#pragma unroll
  for (int mi = 0; mi < 4; ++mi)
#pragma unroll
    for (int ni = 0; ni < 2; ++ni) acc[mi][ni] = (f32x4){0.f, 0.f, 0.f, 0.f};

#pragma unroll
  for (int kh = 0; kh < NKH; ++kh) {
    bf16x8v bfr[2];
#pragma unroll
    for (int ni = 0; ni < 2; ++ni)
      bfr[ni] = *(const bf16x8v*)(bb + ni * 16 * ROWB + kh * 64);
    const int kx = ((kh << 6) + klo) ^ sx;
    bf16x8v af[4];
#pragma unroll
    for (int mi = 0; mi < 4; ++mi)
      af[mi] = *(const bf16x8v*)(smem + arow0 + mi * 16 * ROWB + kx);
#pragma unroll
    for (int mi = 0; mi < 4; ++mi)
#pragma unroll
      for (int ni = 0; ni < 2; ++ni)
        acc[mi][ni] = __builtin_amdgcn_mfma_f32_16x16x32_bf16(
            af[mi], bfr[ni], acc[mi][ni], 0, 0, 0);
  }

  const int prow = p0 + wm * 64 + ((l >> 4) << 2);
  const int col0 = n0 + wn * 32 + l15;
#pragma unroll
  for (int ni = 0; ni < 2; ++ni) {
    int cn = col0 + ni * 16;
    float bias = (cn < Cout) ? br[cn] : bi[cn - Cout];
#pragma unroll
    for (int mi = 0; mi < 4; ++mi)
#pragma unroll
      for (int j = 0; j < 4; ++j) {
        int m = prow + mi * 16 + j;
        if (m < M)
          C[(size_t)m * N + cn] =
              __float2bfloat16(fmaxf(acc[mi][ni][j] + bias, 0.f));
      }
  }
}

// ---- FC --------------------------------------------------------------------
__global__ __launch_bounds__(256) void fc_kernel(
    const __hip_bfloat16* __restrict__ a5, const float* __restrict__ fcw,
    const float* __restrict__ fcb, float* __restrict__ out) {
  int bc = blockIdx.x * 4 + (threadIdx.x >> 6);
  int b = bc >> 6, c = bc & 63;
  int lane = threadIdx.x & 63;
  const __hip_bfloat16* base = a5 + (size_t)b * 625 * 128;
  float sr = 0.f, si = 0.f;
  for (int p = lane; p < 625; p += 64) {
    float wv = fcw[p];
    sr += __bfloat162float(base[(size_t)p * 128 + c]) * wv;
    si += __bfloat162float(base[(size_t)p * 128 + 64 + c]) * wv;
  }
#pragma unroll
  for (int s = 32; s > 0; s >>= 1) {
    sr += __shfl_down(sr, s);
    si += __shfl_down(si, s);
  }
  if (lane == 0) {
    out[bc] = sr + fcb[0];
    out[256 + bc] = si;
  }
}

extern "C" void kernel_launch(void* const* d_in, const int* in_sizes, int n_in,
                              void* d_out, int out_size, void* d_ws,
                              size_t ws_size, hipStream_t stream) {
  const float* xr = (const float*)d_in[0];
  const float* xi = (const float*)d_in[1];
  const float* w1r = (const float*)d_in[2];
  const float* w1i = (const float*)d_in[3];
  const float* b1r = (const float*)d_in[4];
  const float* b1i = (const float*)d_in[5];
  const float* w2r = (const float*)d_in[6];
  const float* w2i = (const float*)d_in[7];
  const float* b2r = (const float*)d_in[8];
  const float* b2i = (const float*)d_in[9];
  const float* w3r = (const float*)d_in[10];
  const float* w3i = (const float*)d_in[11];
  const float* b3r = (const float*)d_in[12];
  const float* b3i = (const float*)d_in[13];
  const float* w4r = (const float*)d_in[14];
  const float* w4i = (const float*)d_in[15];
  const float* b4r = (const float*)d_in[16];
  const float* b4i = (const float*)d_in[17];
  const float* w5r = (const float*)d_in[18];
  const float* w5i = (const float*)d_in[19];
  const float* b5r = (const float*)d_in[20];
  const float* b5i = (const float*)d_in[21];
  const float* fcw = (const float*)d_in[22];
  const float* fcb = (const float*)d_in[23];
  float* out = (float*)d_out;

  float* ws = (float*)d_ws;
  __hip_bfloat16* wt2b = (__hip_bfloat16*)(ws + 5184);     // 663552 bf16
  __hip_bfloat16* w3b = (__hip_bfloat16*)(ws + 336960);    // 32768 bf16
  __hip_bfloat16* w4b = (__hip_bfloat16*)(ws + 353344);    // 65536 bf16
  __hip_bfloat16* w5b = (__hip_bfloat16*)(ws + 386112);    // 32768 bf16
  __hip_bfloat16* xp = (__hip_bfloat16*)(ws + 402496);     // 3748096 bf16
  __hip_bfloat16* a2 = (__hip_bfloat16*)(ws + 2276544);    // 3359232 bf16
  __hip_bfloat16* a4 = (__hip_bfloat16*)(ws + 3956160);    // 6718464 bf16
  __hip_bfloat16* a5 = (__hip_bfloat16*)(ws + 7315392);    // 320000 bf16
  __hip_bfloat16* w1b = (__hip_bfloat16*)(ws + 7475392);   // 16384 bf16
  // bf16 partials alias the a4 region (dead until fused34; stream-ordered)
  __hip_bfloat16* part = (__hip_bfloat16*)(ws + 3956160);

  prep_fused<<<dim3(4999), 256, 0, stream>>>(
      w1r, w1i, w2r, w2i, w3r, w3i, w4r, w4i, w5r, w5i, w1b, wt2b, w3b, w4b,
      w5b, (uint4*)xp);

  l1_fused<<<dim3(206), 512, 0, stream>>>(xr, xi, w1b, b1r, b1i, xp);
  cconv2_ksplit<<<dim3(206, 2), 256, 0, stream>>>(xp, wt2b, part);
  reduce_a2<<<dim3(3281), 256, 0, stream>>>(
      (const uint2*)part, (const uint2*)(part + 3359232), b2r, b2i, a2);
  gemm_fused34<<<dim3(206), 512, 0, stream>>>(a2, w3b, w4b, b3r, b3i, b4r,
                                              b4i, a4);
  gemm_bg<256, 1><<<dim3(20, 1), 512, 0, stream>>>(a4, w5b, b5r, b5i, a5,
                                                   2500, 128, 64);
  fc_kernel<<<dim3(64), 256, 0, stream>>>(a5, fcw, fcb, out);
}

// Round 17
// 112.785 us; speedup vs baseline: 1.0648x; 1.0648x over previous
//
#include <hip/hip_runtime.h>
#include <hip/hip_bf16.h>

typedef __bf16 bf16x8v __attribute__((ext_vector_type(8)));
typedef float f32x4 __attribute__((ext_vector_type(4)));

#define GLD16(gp, loff)                                                     \
  __builtin_amdgcn_global_load_lds(                                         \
      (const __attribute__((address_space(1))) void*)(gp),                  \
      (__attribute__((address_space(3))) void*)(smem + (loff)), 16, 0, 0)

// ---------------------------------------------------------------------------
// Pipeline:
//  Aim  : [26244][256] bf16 im2col (aliases a4 region; dead until fused34).
//  xp   : [b][q:11^4][64] padded L1 out (bf16, zero halo) via gemm_l1 MFMA.
//  part : 2 x [26244][128] bf16 L2 partials — DEDICATED region (fused34
//         reads part while writing a4, must not alias).
//  a4   : [26244][256] bf16;  a5 : [b*625][128] bf16
//  L2: r13-proven grid(206,2) K-split, 4 waves 2Mx2N (64x64), 2x32KB dbuf.
//  fused34 stages its a2-tile from part0+part1+bias2+relu (reduce_a2 gone).
// ---------------------------------------------------------------------------

__global__ __launch_bounds__(256) void prep_fused(
    const float* __restrict__ w1r, const float* __restrict__ w1i,
    const float* __restrict__ w2r, const float* __restrict__ w2i,
    const float* __restrict__ w3r, const float* __restrict__ w3i,
    const float* __restrict__ w4r, const float* __restrict__ w4i,
    const float* __restrict__ w5r, const float* __restrict__ w5i,
    __hip_bfloat16* __restrict__ w1b, __hip_bfloat16* __restrict__ wt2b,
    __hip_bfloat16* __restrict__ w3b, __hip_bfloat16* __restrict__ w4b,
    __hip_bfloat16* __restrict__ w5b, uint4* __restrict__ xpz) {
  const int bx = blockIdx.x;
  const int tid = threadIdx.x;
  auto pack11 = [](const float* wr, const float* wi, __hip_bfloat16* dst,
                   int Cout, int Cin, int idx) {
    int k2 = 2 * Cin;
    int k = idx % k2, n = idx / k2;
    int ci = (k < Cin) ? k : k - Cin;
    int co = (n < Cout) ? n : n - Cout;
    int widx = co * Cin + ci;
    float v;
    if (n < Cout) v = (k < Cin) ? wr[widx] : -wi[widx];
    else          v = (k < Cin) ? wi[widx] :  wr[widx];
    dst[idx] = __float2bfloat16(v);
  };
  if (bx < 1831) {                       // zero xp (incl. halo), 7.5 MB
    int i = bx * 256 + tid;
    if (i < 468512) xpz[i] = make_uint4(0, 0, 0, 0);
  } else if (bx < 4423) {                // wt2b taps 0..80: B[t][n:128][k:64]
    int idx = (bx - 1831) * 256 + tid;
    int k = idx & 63, n = (idx >> 6) & 127, t = idx >> 13;
    int ci = k & 31, kin_i = k >> 5;
    int co = n & 63, out_i = n >> 6;
    int widx = (co * 32 + ci) * 81 + t;
    float v;
    if (out_i == 0) v = (kin_i == 0) ? w2r[widx] : -w2i[widx];
    else            v = (kin_i == 0) ? w2i[widx] :  w2r[widx];
    wt2b[idx] = __float2bfloat16(v);
  } else if (bx < 4487) {                // w1b: [n:64][k:256]
    int idx = (bx - 4423) * 256 + tid;
    int n = idx >> 8, k = idx & 255;
    int t = k >> 1, c = k & 1, co = n & 31;
    float v = 0.f;
    if (t < 81) {
      if (n < 32) v = c ? -w1i[co * 81 + t] : w1r[co * 81 + t];
      else        v = c ?  w1r[co * 81 + t] : w1i[co * 81 + t];
    }
    w1b[idx] = __float2bfloat16(v);
  } else if (bx < 4615) {
    pack11(w3r, w3i, w3b, 128, 64, (bx - 4487) * 256 + tid);
  } else if (bx < 4871) {
    pack11(w4r, w4i, w4b, 128, 128, (bx - 4615) * 256 + tid);
  } else {
    pack11(w5r, w5i, w5b, 64, 128, (bx - 4871) * 256 + tid);
  }
}

// ---- im2col for L1: Aim[m][256] bf16, k=2t+{r,i}, zeros for k>=162. --------
__global__ __launch_bounds__(256) void im2col_l1(
    const float* __restrict__ xr, const float* __restrict__ xi,
    __hip_bfloat16* __restrict__ Aim) {
  __shared__ uint lds[8192];  // 32 KB
  const int tid = threadIdx.x;
  const int row = tid & 63;
  const int tg = tid >> 6;
  const int m0 = blockIdx.x * 64;
  int m = m0 + row;
  if (m > 26243) m = 26243;
  int b = m / 6561, p = m % 6561;
  int d1 = p / 729, r = p % 729;
  int d2 = r / 81;
  r %= 81;
  int d3 = r / 9, d4 = r % 9;
  const int base = b * 160000 + d1 * 16000 + d2 * 800 + d3 * 40 + d4 * 2;
  const int xorv = (row & 31) << 2;
  const int rbase = row << 7;

  const int tend = (tg == 3) ? 81 : tg * 21 + 21;
  for (int t = tg * 21; t < tend; ++t) {
    int j1 = t / 27, j2 = (t / 9) % 3, j3 = (t / 3) % 3, j4 = t % 3;
    int xo = base + j1 * 8000 + j2 * 400 + j3 * 20 + j4;
    __hip_bfloat16 h2[2] = {__float2bfloat16(xr[xo]),
                            __float2bfloat16(xi[xo])};
    lds[rbase + (t ^ xorv)] = *(const uint*)h2;
  }
  for (int t = 81 + tg; t < 128; t += 4) lds[rbase + (t ^ xorv)] = 0u;
  __syncthreads();

  uint4* dst = (uint4*)(Aim + (size_t)m0 * 256);
#pragma unroll
  for (int ph = 0; ph < 8; ++ph) {
    int W = ph * 4096 + tid * 16;
    int rw = W >> 9;
    int c4 = (W & 511) >> 2;
    int li = (rw << 7) + (c4 ^ ((rw & 31) << 2));
    uint4 v = {lds[li], lds[li + 1], lds[li + 2], lds[li + 3]};
    dst[W >> 4] = v;
  }
}

// ---- L1 GEMM: M=26244, N=64, K=256. 8 waves 4Mx2N; halo-scatter epilogue. --
__global__ __launch_bounds__(512) void gemm_l1(
    const __hip_bfloat16* __restrict__ Aim, const __hip_bfloat16* __restrict__ Bm,
    const float* __restrict__ br, const float* __restrict__ bi,
    __hip_bfloat16* __restrict__ xp) {
  __shared__ __align__(128) char smem[65536];  // 128 rows x 512 B
  const int tid = threadIdx.x, l = tid & 63, w = tid >> 6;
  const int wm = w & 3, wn = w >> 2;  // 4M x 2N
  const int p0 = blockIdx.x * 128;

  const char* aB = (const char*)Aim;
#pragma unroll
  for (int g = 0; g < 8; ++g) {
    int W = (w * 8 + g) * 1024 + (l << 4);
    int row = W >> 9;
    int cb = W & 511;
    int m = p0 + row;
    if (m > 26243) m = 26243;
    GLD16(aB + (size_t)m * 512 + (cb ^ ((row & 7) << 4)), W);
  }
  asm volatile("s_waitcnt vmcnt(0)" ::: "memory");
  __syncthreads();

  const int l15 = l & 15;
  const int klo = (l >> 4) << 4;
  const int sx = (l & 7) << 4;
  const int arow0 = (wm * 32 + l15) * 512;
  const char* bb = (const char*)Bm + (size_t)(wn * 32 + l15) * 512 + klo;

  f32x4 acc[2][2];
#pragma unroll
  for (int mi = 0; mi < 2; ++mi)
#pragma unroll
    for (int ni = 0; ni < 2; ++ni) acc[mi][ni] = (f32x4){0.f, 0.f, 0.f, 0.f};

#pragma unroll
  for (int kh = 0; kh < 8; ++kh) {
    bf16x8v bfr[2];
#pragma unroll
    for (int ni = 0; ni < 2; ++ni)
      bfr[ni] = *(const bf16x8v*)(bb + ni * 16 * 512 + kh * 64);
    const int kx = ((kh << 6) + klo) ^ sx;
    bf16x8v af[2];
#pragma unroll
    for (int mi = 0; mi < 2; ++mi)
      af[mi] = *(const bf16x8v*)(smem + arow0 + mi * 8192 + kx);
#pragma unroll
    for (int mi = 0; mi < 2; ++mi)
#pragma unroll
      for (int ni = 0; ni < 2; ++ni)
        acc[mi][ni] = __builtin_amdgcn_mfma_f32_16x16x32_bf16(
            af[mi], bfr[ni], acc[mi][ni], 0, 0, 0);
  }

  const int prow = p0 + wm * 32 + ((l >> 4) << 2);
  const int col0 = wn * 32 + l15;
#pragma unroll
  for (int ni = 0; ni < 2; ++ni) {
    int cn = col0 + ni * 16;
    float bias = (cn < 32) ? br[cn] : bi[cn - 32];
#pragma unroll
    for (int mi = 0; mi < 2; ++mi)
#pragma unroll
      for (int j = 0; j < 4; ++j) {
        int m = prow + mi * 16 + j;
        if (m < 26244) {
          int b = m / 6561, p = m % 6561;
          int d1 = p / 729, r = p % 729;
          int d2 = r / 81;
          r %= 81;
          int d3 = r / 9, d4 = r % 9;
          int q = (((d1 + 1) * 11 + (d2 + 1)) * 11 + (d3 + 1)) * 11 + (d4 + 1);
          xp[((size_t)(b * 14641 + q)) * 64 + cn] =
              __float2bfloat16(fmaxf(acc[mi][ni][j] + bias, 0.f));
        }
      }
  }
}

// ---- Layer 2: r13-proven. K-split grid (206,2); 4 waves 2Mx2N (64x64);
//      BK=64; 2x32KB buffers; bf16 partial store. ---------------------------
__global__ __launch_bounds__(256) void cconv2_ksplit(
    const __hip_bfloat16* __restrict__ xp, const __hip_bfloat16* __restrict__ wb,
    __hip_bfloat16* __restrict__ part) {
  __shared__ __align__(128) char smem[65536];  // 2 x (A 16KB | B 16KB)
  const int tid = threadIdx.x;
  const int l = tid & 63, w = tid >> 6;        // 4 waves
  const int wm = w & 1, wn = w >> 1;           // 2M x 2N, wave tile 64x64
  const int m0 = blockIdx.x * 128;
  const int ky = blockIdx.y;                   // K-half: taps [0,41) / [41,81)

  const int swz = ((l & 7) ^ (l >> 3)) << 4;
  const char* xpB = (const char*)xp;
  const char* wB = (const char*)wb;
  int q00[4], rbB[4];
#pragma unroll
  for (int c = 0; c < 4; ++c) {
    int row = w * 32 + c * 8 + (l >> 3);
    int m = m0 + row;
    if (m > 26243) m = 26243;
    int b = m / 6561, p = m % 6561;
    int d1 = p / 729, r = p % 729;
    int d2 = r / 81;
    r %= 81;
    int d3 = r / 9, d4 = r % 9;
    q00[c] = b * 14641 + ((d1 * 11 + d2) * 11 + d3) * 11 + d4;
    rbB[c] = row * 128 + swz;
  }

  const int l15 = l & 15;
  const int klo = (l >> 4) << 4;
  const int sx = (l & 7) << 4;
  const int arow0 = (wm * 64 + l15) * 128;
  const int brow0 = 16384 + (wn * 64 + l15) * 128;

  f32x4 acc[4][4];
#pragma unroll
  for (int mi = 0; mi < 4; ++mi)
#pragma unroll
    for (int ni = 0; ni < 4; ++ni) acc[mi][ni] = (f32x4){0.f, 0.f, 0.f, 0.f};

  auto stage = [&](int t, int nb) {
    int j1 = t / 27, j2 = (t / 9) % 3, j3 = (t / 3) % 3, j4 = t % 3;
    int delta = ((j1 * 11 + j2) * 11 + j3) * 11 + j4;
#pragma unroll
    for (int c = 0; c < 4; ++c) {
      GLD16(xpB + (((size_t)(q00[c] + delta)) << 7) + swz,
            nb + w * 4096 + c * 1024);
      GLD16(wB + (((size_t)t) << 14) + rbB[c],
            nb + 16384 + w * 4096 + c * 1024);
    }
  };

  const int t0 = ky * 41;            // 0 or 41
  const int nt = 41 - ky;            // 41 or 40

  stage(t0, 0);

  for (int ti = 0; ti < nt; ++ti) {
    asm volatile("s_waitcnt vmcnt(0)" ::: "memory");
    __builtin_amdgcn_s_barrier();
    if (ti + 1 < nt) stage(t0 + ti + 1, ((ti + 1) & 1) * 32768);
    const char* sb = smem + (ti & 1) * 32768;
#pragma unroll
    for (int kh = 0; kh < 2; ++kh) {
      const int kx = ((kh << 6) + klo) ^ sx;
      bf16x8v af[4], bfr[4];
#pragma unroll
      for (int mi = 0; mi < 4; ++mi)
        af[mi] = *(const bf16x8v*)(sb + arow0 + mi * 2048 + kx);
#pragma unroll
      for (int ni = 0; ni < 4; ++ni)
        bfr[ni] = *(const bf16x8v*)(sb + brow0 + ni * 2048 + kx);
#pragma unroll
      for (int mi = 0; mi < 4; ++mi)
#pragma unroll
        for (int ni = 0; ni < 4; ++ni)
          acc[mi][ni] = __builtin_amdgcn_mfma_f32_16x16x32_bf16(
              af[mi], bfr[ni], acc[mi][ni], 0, 0, 0);
    }
  }

  __hip_bfloat16* pp = part + (size_t)ky * 3359232;
  const int prow = m0 + wm * 64 + ((l >> 4) << 2);
  const int col0 = wn * 64 + l15;
#pragma unroll
  for (int ni = 0; ni < 4; ++ni) {
    int cn = col0 + ni * 16;
#pragma unroll
    for (int mi = 0; mi < 4; ++mi)
#pragma unroll
      for (int j = 0; j < 4; ++j) {
        int m = prow + mi * 16 + j;
        if (m < 26244)
          pp[(size_t)m * 128 + cn] = __float2bfloat16(acc[mi][ni][j]);
      }
  }
}

// ---- L3+L4 fused (+L2 reduce fused into staging):
//      a2tile = bf16(relu(p0+p1+bias2)) -> L3 -> relu a3 (LDS) -> L4 -> a4. -
__global__ __launch_bounds__(512) void gemm_fused34(
    const __hip_bfloat16* __restrict__ p0, const __hip_bfloat16* __restrict__ p1,
    const __hip_bfloat16* __restrict__ w3, const __hip_bfloat16* __restrict__ w4,
    const float* __restrict__ b2r, const float* __restrict__ b2i,
    const float* __restrict__ b3r, const float* __restrict__ b3i,
    const float* __restrict__ b4r, const float* __restrict__ b4i,
    __hip_bfloat16* __restrict__ a4) {
  __shared__ __align__(128) char smem[98304];  // a2 tile 32KB | a3 tile 64KB
  const int tid = threadIdx.x, l = tid & 63, w = tid >> 6;
  const int wm = w & 1, wn = w >> 1;  // 2M x 4N
  const int pfix = blockIdx.x * 128;

  // ---- stage a2 tile from bf16 partials + bias2 + relu (reduce fused) -----
  {
    int r = tid >> 2;                 // 0..127 tile row
    int cb = (tid & 3) * 32;          // 32 channels per thread
    int m = pfix + r;
    if (m > 26243) m = 26243;
    const uint2* q0 = (const uint2*)(p0 + (size_t)m * 128 + cb);
    const uint2* q1 = (const uint2*)(p1 + (size_t)m * 128 + cb);
    __hip_bfloat16 tmp[32];
#pragma unroll
    for (int i = 0; i < 8; ++i) {
      uint2 ua = q0[i], ub = q1[i];
      const __hip_bfloat16* a = (const __hip_bfloat16*)&ua;
      const __hip_bfloat16* b = (const __hip_bfloat16*)&ub;
#pragma unroll
      for (int e = 0; e < 4; ++e) {
        int cn = cb + i * 4 + e;
        float bias = (cn < 64) ? b2r[cn] : b2i[cn - 64];
        float s = __bfloat162float(a[e]) + __bfloat162float(b[e]) + bias;
        tmp[i * 4 + e] = __float2bfloat16(fmaxf(s, 0.f));
      }
    }
    const int rs = (r & 7) << 4;
#pragma unroll
    for (int s4 = 0; s4 < 4; ++s4) {
      int col = cb * 2 + s4 * 16;     // byte col within 256B row
      *(uint4*)(smem + r * 256 + (col ^ rs)) = ((const uint4*)tmp)[s4];
    }
  }
  __syncthreads();

  const int l15 = l & 15;
  const int klo = (l >> 4) << 4;
  const int sx = (l & 7) << 4;

  f32x4 acc[4][4];
#pragma unroll
  for (int mi = 0; mi < 4; ++mi)
#pragma unroll
    for (int ni = 0; ni < 4; ++ni) acc[mi][ni] = (f32x4){0.f, 0.f, 0.f, 0.f};

  // ---- L3: K=128, A from smem[0..32K), B3 from global ---------------------
  {
    const int arow3 = (wm * 64 + l15) * 256;
    const char* b3b = (const char*)w3 + (size_t)(wn * 64 + l15) * 256 + klo;
#pragma unroll
    for (int kh = 0; kh < 4; ++kh) {
      const int kx = ((kh << 6) + klo) ^ sx;
      bf16x8v af[4], bfr[4];
#pragma unroll
      for (int mi = 0; mi < 4; ++mi)
        af[mi] = *(const bf16x8v*)(smem + arow3 + mi * 4096 + kx);
#pragma unroll
      for (int ni = 0; ni < 4; ++ni)
        bfr[ni] = *(const bf16x8v*)(b3b + ni * 4096 + kh * 64);
#pragma unroll
      for (int mi = 0; mi < 4; ++mi)
#pragma unroll
        for (int ni = 0; ni < 4; ++ni)
          acc[mi][ni] = __builtin_amdgcn_mfma_f32_16x16x32_bf16(
              af[mi], bfr[ni], acc[mi][ni], 0, 0, 0);
    }
  }

  __syncthreads();
  {
    const int lrow = wm * 64 + ((l >> 4) << 2);
    const int col0 = wn * 64 + l15;
#pragma unroll
    for (int ni = 0; ni < 4; ++ni) {
      int cn = col0 + ni * 16;
      float bias = (cn < 128) ? b3r[cn] : b3i[cn - 128];
#pragma unroll
      for (int mi = 0; mi < 4; ++mi) {
        int row = lrow + mi * 16;
#pragma unroll
        for (int j = 0; j < 4; ++j) {
          float v = fmaxf(acc[mi][ni][j] + bias, 0.f);
          int addr = (32768 + (row + j) * 512 + cn * 2) ^ (((row + j) & 7) << 4);
          *(__hip_bfloat16*)(smem + addr) = __float2bfloat16(v);
        }
      }
    }
  }
  __syncthreads();

  // ---- L4: K=256, A from a3 tile @32768, B4 from global -------------------
#pragma unroll
  for (int mi = 0; mi < 4; ++mi)
#pragma unroll
    for (int ni = 0; ni < 4; ++ni) acc[mi][ni] = (f32x4){0.f, 0.f, 0.f, 0.f};
  {
    const int arow4 = 32768 + (wm * 64 + l15) * 512;
    const char* b4b = (const char*)w4 + (size_t)(wn * 64 + l15) * 512 + klo;
#pragma unroll
    for (int kh = 0; kh < 8; ++kh) {
      const int kx = ((kh << 6) + klo) ^ sx;
      bf16x8v af[4], bfr[4];
#pragma unroll
      for (int mi = 0; mi < 4; ++mi)
        af[mi] = *(const bf16x8v*)(smem + arow4 + mi * 8192 + kx);
#pragma unroll
      for (int ni = 0; ni < 4; ++ni)
        bfr[ni] = *(const bf16x8v*)(b4b + ni * 8192 + kh * 64);
#pragma unroll
      for (int mi = 0; mi < 4; ++mi)
#pragma unroll
        for (int ni = 0; ni < 4; ++ni)
          acc[mi][ni] = __builtin_amdgcn_mfma_f32_16x16x32_bf16(
              af[mi], bfr[ni], acc[mi][ni], 0, 0, 0);
    }
  }

  {
    const int prow = pfix + wm * 64 + ((l >> 4) << 2);
    const int col0 = wn * 64 + l15;
#pragma unroll
    for (int ni = 0; ni < 4; ++ni) {
      int cn = col0 + ni * 16;
      float bias = (cn < 128) ? b4r[cn] : b4i[cn - 128];
#pragma unroll
      for (int mi = 0; mi < 4; ++mi)
#pragma unroll
        for (int j = 0; j < 4; ++j) {
          int m = prow + mi * 16 + j;
          if (m < 26244)
            a4[(size_t)m * 256 + cn] =
                __float2bfloat16(fmaxf(acc[mi][ni][j] + bias, 0.f));
        }
    }
  }
}

// ---- L5 GEMM ---------------------------------------------------------------
template <int K, int S2>
__global__ __launch_bounds__(512) void gemm_bg(
    const __hip_bfloat16* __restrict__ A, const __hip_bfloat16* __restrict__ Bm,
    const float* __restrict__ br, const float* __restrict__ bi,
    __hip_bfloat16* __restrict__ C, int M, int N, int Cout) {
  constexpr int ROWB = 2 * K;
  constexpr int NKH = K / 32;
  constexpr int LG = (K == 128) ? 8 : 9;
  __shared__ __align__(128) char smem[128 * ROWB];
  const int tid = threadIdx.x, l = tid & 63, w = tid >> 6;
  const int wm = w & 1, wn = w >> 1;
  const int p0 = blockIdx.x * 128, n0 = blockIdx.y * 128;

  const char* aB = (const char*)A;
#pragma unroll
  for (int g = 0; g < NKH; ++g) {
    int W = (w * NKH + g) * 1024 + (l << 4);
    int row = W >> LG;
    int cb = W & (ROWB - 1);
    int m = p0 + row;
    if (m >= M) m = M - 1;
    int srcrow;
    if (S2) {
      int bb_ = m / 625, r = m % 625;
      int d1 = r / 125;
      r %= 125;
      int d2 = r / 25;
      r %= 25;
      int d3 = r / 5, d4 = r % 5;
      srcrow = bb_ * 6561 + d1 * 1458 + d2 * 162 + d3 * 18 + d4 * 2;
    } else {
      srcrow = m;
    }
    GLD16(aB + (size_t)srcrow * ROWB + (cb ^ ((row & 7) << 4)), W);
  }
  asm volatile("s_waitcnt vmcnt(0)" ::: "memory");
  __syncthreads();

  const int l15 = l & 15;
  const int klo = (l >> 4) << 4;
  const int sx = (l & 7) << 4;
  const int arow0 = (wm * 64 + l15) * ROWB;
  const char* bb = (const char*)Bm + (size_t)(n0 + wn * 32 + l15) * ROWB + klo;

  f32x4 acc[4][2];
#pragma unroll
  for (int mi = 0; mi < 4; ++mi)
#pragma unroll
    for (int ni = 0; ni < 2; ++ni) acc[mi][ni] = (f32x4){0.f, 0.f, 0.f, 0.f};

#pragma unroll
  for (int kh = 0; kh < NKH; ++kh) {
    bf16x8v bfr[2];
#pragma unroll
    for (int ni = 0; ni < 2; ++ni)
      bfr[ni] = *(const bf16x8v*)(bb + ni * 16 * ROWB + kh * 64);
    const int kx = ((kh << 6) + klo) ^ sx;
    bf16x8v af[4];
#pragma unroll
    for (int mi = 0; mi < 4; ++mi)
      af[mi] = *(const bf16x8v*)(smem + arow0 + mi * 16 * ROWB + kx);
#pragma unroll
    for (int mi = 0; mi < 4; ++mi)
#pragma unroll
      for (int ni = 0; ni < 2; ++ni)
        acc[mi][ni] = __builtin_amdgcn_mfma_f32_16x16x32_bf16(
            af[mi], bfr[ni], acc[mi][ni], 0, 0, 0);
  }

  const int prow = p0 + wm * 64 + ((l >> 4) << 2);
  const int col0 = n0 + wn * 32 + l15;
#pragma unroll
  for (int ni = 0; ni < 2; ++ni) {
    int cn = col0 + ni * 16;
    float bias = (cn < Cout) ? br[cn] : bi[cn - Cout];
#pragma unroll
    for (int mi = 0; mi < 4; ++mi)
#pragma unroll
      for (int j = 0; j < 4; ++j) {
        int m = prow + mi * 16 + j;
        if (m < M)
          C[(size_t)m * N + cn] =
              __float2bfloat16(fmaxf(acc[mi][ni][j] + bias, 0.f));
      }
  }
}

// ---- FC --------------------------------------------------------------------
__global__ __launch_bounds__(256) void fc_kernel(
    const __hip_bfloat16* __restrict__ a5, const float* __restrict__ fcw,
    const float* __restrict__ fcb, float* __restrict__ out) {
  int bc = blockIdx.x * 4 + (threadIdx.x >> 6);
  int b = bc >> 6, c = bc & 63;
  int lane = threadIdx.x & 63;
  const __hip_bfloat16* base = a5 + (size_t)b * 625 * 128;
  float sr = 0.f, si = 0.f;
  for (int p = lane; p < 625; p += 64) {
    float wv = fcw[p];
    sr += __bfloat162float(base[(size_t)p * 128 + c]) * wv;
    si += __bfloat162float(base[(size_t)p * 128 + 64 + c]) * wv;
  }
#pragma unroll
  for (int s = 32; s > 0; s >>= 1) {
    sr += __shfl_down(sr, s);
    si += __shfl_down(si, s);
  }
  if (lane == 0) {
    out[bc] = sr + fcb[0];
    out[256 + bc] = si;
  }
}

extern "C" void kernel_launch(void* const* d_in, const int* in_sizes, int n_in,
                              void* d_out, int out_size, void* d_ws,
                              size_t ws_size, hipStream_t stream) {
  const float* xr = (const float*)d_in[0];
  const float* xi = (const float*)d_in[1];
  const float* w1r = (const float*)d_in[2];
  const float* w1i = (const float*)d_in[3];
  const float* b1r = (const float*)d_in[4];
  const float* b1i = (const float*)d_in[5];
  const float* w2r = (const float*)d_in[6];
  const float* w2i = (const float*)d_in[7];
  const float* b2r = (const float*)d_in[8];
  const float* b2i = (const float*)d_in[9];
  const float* w3r = (const float*)d_in[10];
  const float* w3i = (const float*)d_in[11];
  const float* b3r = (const float*)d_in[12];
  const float* b3i = (const float*)d_in[13];
  const float* w4r = (const float*)d_in[14];
  const float* w4i = (const float*)d_in[15];
  const float* b4r = (const float*)d_in[16];
  const float* b4i = (const float*)d_in[17];
  const float* w5r = (const float*)d_in[18];
  const float* w5i = (const float*)d_in[19];
  const float* b5r = (const float*)d_in[20];
  const float* b5i = (const float*)d_in[21];
  const float* fcw = (const float*)d_in[22];
  const float* fcb = (const float*)d_in[23];
  float* out = (float*)d_out;

  float* ws = (float*)d_ws;
  __hip_bfloat16* wt2b = (__hip_bfloat16*)(ws + 5184);     // 663552 bf16
  __hip_bfloat16* w3b = (__hip_bfloat16*)(ws + 336960);    // 32768 bf16
  __hip_bfloat16* w4b = (__hip_bfloat16*)(ws + 353344);    // 65536 bf16
  __hip_bfloat16* w5b = (__hip_bfloat16*)(ws + 386112);    // 16384 bf16
  __hip_bfloat16* xp = (__hip_bfloat16*)(ws + 402496);     // 3748096 bf16
  __hip_bfloat16* a4 = (__hip_bfloat16*)(ws + 3956160);    // 6718464 bf16
  __hip_bfloat16* a5 = (__hip_bfloat16*)(ws + 7315392);    // 320000 bf16
  __hip_bfloat16* w1b = (__hip_bfloat16*)(ws + 7475392);   // 16384 bf16
  // part: DEDICATED region (fused34 reads it while writing a4)
  __hip_bfloat16* part = (__hip_bfloat16*)(ws + 7483584);  // 6718464 bf16
  // Aim aliases a4 region (dead until fused34; tail overruns into a5,
  // which is rewritten later by gemm_bg)
  __hip_bfloat16* Aim = (__hip_bfloat16*)(ws + 3956160);

  prep_fused<<<dim3(4999), 256, 0, stream>>>(
      w1r, w1i, w2r, w2i, w3r, w3i, w4r, w4i, w5r, w5i, w1b, wt2b, w3b, w4b,
      w5b, (uint4*)xp);

  im2col_l1<<<dim3(411), 256, 0, stream>>>(xr, xi, Aim);
  gemm_l1<<<dim3(206), 512, 0, stream>>>(Aim, w1b, b1r, b1i, xp);
  cconv2_ksplit<<<dim3(206, 2), 256, 0, stream>>>(xp, wt2b, part);
  gemm_fused34<<<dim3(206), 512, 0, stream>>>(
      part, part + 3359232, w3b, w4b, b2r, b2i, b3r, b3i, b4r, b4i, a4);
  gemm_bg<256, 1><<<dim3(20, 1), 512, 0, stream>>>(a4, w5b, b5r, b5i, a5,
                                                   2500, 128, 64);
  fc_kernel<<<dim3(64), 256, 0, stream>>>(a5, fcw, fcb, out);
}

// Round 19
// 108.517 us; speedup vs baseline: 1.1067x; 1.0393x over previous
//
#include <hip/hip_runtime.h>
#include <hip/hip_bf16.h>

typedef __bf16 bf16x8v __attribute__((ext_vector_type(8)));
typedef float f32x4 __attribute__((ext_vector_type(4)));

#define GLD16(gp, loff)                                                     \
  __builtin_amdgcn_global_load_lds(                                         \
      (const __attribute__((address_space(1))) void*)(gp),                  \
      (__attribute__((address_space(3))) void*)(smem + (loff)), 16, 0, 0)

// ---------------------------------------------------------------------------
// Pipeline:
//  Aim  : [26244][256] bf16 im2col (aliases a4 region; dead until fused34).
//  xp   : [b][q:11^4][64] padded L1 out (bf16). prep zeroes ONLY the halo
//         rows (interior fully rewritten by gemm_l1 each call).
//  part : 2 x [26244][128] bf16 L2 partials — dedicated region.
//  a4   : [26244][256] bf16;  a5 : [b*625][128] bf16
//  prep_fused also contains im2col (independent; one launch fewer).
//  gemm_l1: LDS-staged epilogue -> 128B-contiguous xp row writes.
//  Branch budget (r18 bugfix): halo 1831 | wt2b 2592 | w1b 64 | w3b 128 |
//  w4b 256 | w5b 128 (=4999) | im2col 411 -> grid 5410.
// ---------------------------------------------------------------------------

__global__ __launch_bounds__(256) void prep_fused(
    const float* __restrict__ xr, const float* __restrict__ xi,
    const float* __restrict__ w1r, const float* __restrict__ w1i,
    const float* __restrict__ w2r, const float* __restrict__ w2i,
    const float* __restrict__ w3r, const float* __restrict__ w3i,
    const float* __restrict__ w4r, const float* __restrict__ w4i,
    const float* __restrict__ w5r, const float* __restrict__ w5i,
    __hip_bfloat16* __restrict__ w1b, __hip_bfloat16* __restrict__ wt2b,
    __hip_bfloat16* __restrict__ w3b, __hip_bfloat16* __restrict__ w4b,
    __hip_bfloat16* __restrict__ w5b, uint4* __restrict__ xpz,
    __hip_bfloat16* __restrict__ Aim) {
  __shared__ uint lds[8192];  // im2col branch only (32 KB)
  const int bx = blockIdx.x;
  const int tid = threadIdx.x;
  auto pack11 = [](const float* wr, const float* wi, __hip_bfloat16* dst,
                   int Cout, int Cin, int idx) {
    int k2 = 2 * Cin;
    int k = idx % k2, n = idx / k2;
    int ci = (k < Cin) ? k : k - Cin;
    int co = (n < Cout) ? n : n - Cout;
    int widx = co * Cin + ci;
    float v;
    if (n < Cout) v = (k < Cin) ? wr[widx] : -wi[widx];
    else          v = (k < Cin) ? wi[widx] :  wr[widx];
    dst[idx] = __float2bfloat16(v);
  };
  if (bx < 1831) {                       // zero xp HALO rows only
    int i = bx * 256 + tid;
    if (i < 468512) {
      int q = (i >> 3) % 14641;
      unsigned e4 = q % 11;
      int r_ = q / 11;
      unsigned e3 = r_ % 11;
      r_ /= 11;
      unsigned e2 = r_ % 11;
      unsigned e1 = r_ / 11;
      bool interior = (e1 - 1u) < 9u && (e2 - 1u) < 9u && (e3 - 1u) < 9u &&
                      (e4 - 1u) < 9u;
      if (!interior) xpz[i] = make_uint4(0, 0, 0, 0);
    }
  } else if (bx < 4423) {                // wt2b taps 0..80: B[t][n:128][k:64]
    int idx = (bx - 1831) * 256 + tid;
    int k = idx & 63, n = (idx >> 6) & 127, t = idx >> 13;
    int ci = k & 31, kin_i = k >> 5;
    int co = n & 63, out_i = n >> 6;
    int widx = (co * 32 + ci) * 81 + t;
    float v;
    if (out_i == 0) v = (kin_i == 0) ? w2r[widx] : -w2i[widx];
    else            v = (kin_i == 0) ? w2i[widx] :  w2r[widx];
    wt2b[idx] = __float2bfloat16(v);
  } else if (bx < 4487) {                // w1b: [n:64][k:256]
    int idx = (bx - 4423) * 256 + tid;
    int n = idx >> 8, k = idx & 255;
    int t = k >> 1, c = k & 1, co = n & 31;
    float v = 0.f;
    if (t < 81) {
      if (n < 32) v = c ? -w1i[co * 81 + t] : w1r[co * 81 + t];
      else        v = c ?  w1r[co * 81 + t] : w1i[co * 81 + t];
    }
    w1b[idx] = __float2bfloat16(v);
  } else if (bx < 4615) {
    pack11(w3r, w3i, w3b, 128, 64, (bx - 4487) * 256 + tid);
  } else if (bx < 4871) {
    pack11(w4r, w4i, w4b, 128, 128, (bx - 4615) * 256 + tid);
  } else if (bx < 4999) {                // w5b: 128x256 = 128 blocks
    pack11(w5r, w5i, w5b, 64, 128, (bx - 4871) * 256 + tid);
  } else {                               // im2col: Aim[m][256] bf16
    const int row = tid & 63;
    const int tg = tid >> 6;
    const int m0 = (bx - 4999) * 64;
    int m = m0 + row;
    if (m > 26243) m = 26243;
    int b = m / 6561, p = m % 6561;
    int d1 = p / 729, r = p % 729;
    int d2 = r / 81;
    r %= 81;
    int d3 = r / 9, d4 = r % 9;
    const int base = b * 160000 + d1 * 16000 + d2 * 800 + d3 * 40 + d4 * 2;
    const int xorv = (row & 31) << 2;
    const int rbase = row << 7;

    const int tend = (tg == 3) ? 81 : tg * 21 + 21;
    for (int t = tg * 21; t < tend; ++t) {
      int j1 = t / 27, j2 = (t / 9) % 3, j3 = (t / 3) % 3, j4 = t % 3;
      int xo = base + j1 * 8000 + j2 * 400 + j3 * 20 + j4;
      __hip_bfloat16 h2[2] = {__float2bfloat16(xr[xo]),
                              __float2bfloat16(xi[xo])};
      lds[rbase + (t ^ xorv)] = *(const uint*)h2;
    }
    for (int t = 81 + tg; t < 128; t += 4) lds[rbase + (t ^ xorv)] = 0u;
    __syncthreads();

    uint4* dst = (uint4*)(Aim + (size_t)m0 * 256);
#pragma unroll
    for (int ph = 0; ph < 8; ++ph) {
      int W = ph * 4096 + tid * 16;
      int rw = W >> 9;
      int c4 = (W & 511) >> 2;
      int li = (rw << 7) + (c4 ^ ((rw & 31) << 2));
      uint4 v = {lds[li], lds[li + 1], lds[li + 2], lds[li + 3]};
      dst[W >> 4] = v;
    }
  }
}

// ---- L1 GEMM: M=26244, N=64, K=256. 8 waves 4Mx2N; LDS-staged epilogue
//      (swizzled) -> 128B-contiguous per-row xp writes. ---------------------
__global__ __launch_bounds__(512) void gemm_l1(
    const __hip_bfloat16* __restrict__ Aim, const __hip_bfloat16* __restrict__ Bm,
    const float* __restrict__ br, const float* __restrict__ bi,
    __hip_bfloat16* __restrict__ xp) {
  __shared__ __align__(128) char smem[65536];  // 128 rows x 512 B
  const int tid = threadIdx.x, l = tid & 63, w = tid >> 6;
  const int wm = w & 3, wn = w >> 2;  // 4M x 2N
  const int p0 = blockIdx.x * 128;

  const char* aB = (const char*)Aim;
#pragma unroll
  for (int g = 0; g < 8; ++g) {
    int W = (w * 8 + g) * 1024 + (l << 4);
    int row = W >> 9;
    int cb = W & 511;
    int m = p0 + row;
    if (m > 26243) m = 26243;
    GLD16(aB + (size_t)m * 512 + (cb ^ ((row & 7) << 4)), W);
  }
  asm volatile("s_waitcnt vmcnt(0)" ::: "memory");
  __syncthreads();

  const int l15 = l & 15;
  const int klo = (l >> 4) << 4;
  const int sx = (l & 7) << 4;
  const int arow0 = (wm * 32 + l15) * 512;
  const char* bb = (const char*)Bm + (size_t)(wn * 32 + l15) * 512 + klo;

  f32x4 acc[2][2];
#pragma unroll
  for (int mi = 0; mi < 2; ++mi)
#pragma unroll
    for (int ni = 0; ni < 2; ++ni) acc[mi][ni] = (f32x4){0.f, 0.f, 0.f, 0.f};

#pragma unroll
  for (int kh = 0; kh < 8; ++kh) {
    bf16x8v bfr[2];
#pragma unroll
    for (int ni = 0; ni < 2; ++ni)
      bfr[ni] = *(const bf16x8v*)(bb + ni * 16 * 512 + kh * 64);
    const int kx = ((kh << 6) + klo) ^ sx;
    bf16x8v af[2];
#pragma unroll
    for (int mi = 0; mi < 2; ++mi)
      af[mi] = *(const bf16x8v*)(smem + arow0 + mi * 8192 + kx);
#pragma unroll
    for (int mi = 0; mi < 2; ++mi)
#pragma unroll
      for (int ni = 0; ni < 2; ++ni)
        acc[mi][ni] = __builtin_amdgcn_mfma_f32_16x16x32_bf16(
            af[mi], bfr[ni], acc[mi][ni], 0, 0, 0);
  }

  // ---- epilogue: acc -> swizzled LDS bf16 tile [128 rows][64 ch] ----------
  __syncthreads();  // A-tile reads complete; reuse smem
  {
    const int lrow0 = wm * 32 + ((l >> 4) << 2);
    const int ch0 = wn * 32 + l15;
#pragma unroll
    for (int ni = 0; ni < 2; ++ni) {
      int ch = ch0 + ni * 16;
      float bias = (ch < 32) ? br[ch] : bi[ch - 32];
#pragma unroll
      for (int mi = 0; mi < 2; ++mi)
#pragma unroll
        for (int j = 0; j < 4; ++j) {
          int row = lrow0 + mi * 16 + j;
          int byteoff =
              row * 128 + ((((ch >> 3) ^ (row & 7)) << 4)) + (ch & 7) * 2;
          *(__hip_bfloat16*)(smem + byteoff) =
              __float2bfloat16(fmaxf(acc[mi][ni][j] + bias, 0.f));
        }
    }
  }
  __syncthreads();
  // ---- coalesced scatter: per xp row one 128B burst (8 lanes x 16B) -------
#pragma unroll
  for (int it = 0; it < 2; ++it) {
    int W = it * 8192 + tid * 16;
    int row = W >> 7;
    int slot = (W & 127) >> 4;
    int m = p0 + row;
    if (m < 26244) {
      uint4 v = *(const uint4*)(smem + row * 128 + ((slot ^ (row & 7)) << 4));
      int b = m / 6561, p = m % 6561;
      int d1 = p / 729, r = p % 729;
      int d2 = r / 81;
      r %= 81;
      int d3 = r / 9, d4 = r % 9;
      int q = (((d1 + 1) * 11 + (d2 + 1)) * 11 + (d3 + 1)) * 11 + (d4 + 1);
      *(uint4*)(xp + ((size_t)(b * 14641 + q)) * 64 + slot * 8) = v;
    }
  }
}

// ---- Layer 2: r13-proven. K-split grid (206,2); 4 waves 2Mx2N (64x64);
//      BK=64; 2x32KB buffers; bf16 partial store. ---------------------------
__global__ __launch_bounds__(256) void cconv2_ksplit(
    const __hip_bfloat16* __restrict__ xp, const __hip_bfloat16* __restrict__ wb,
    __hip_bfloat16* __restrict__ part) {
  __shared__ __align__(128) char smem[65536];  // 2 x (A 16KB | B 16KB)
  const int tid = threadIdx.x;
  const int l = tid & 63, w = tid >> 6;        // 4 waves
  const int wm = w & 1, wn = w >> 1;           // 2M x 2N, wave tile 64x64
  const int m0 = blockIdx.x * 128;
  const int ky = blockIdx.y;                   // K-half: taps [0,41) / [41,81)

  const int swz = ((l & 7) ^ (l >> 3)) << 4;
  const char* xpB = (const char*)xp;
  const char* wB = (const char*)wb;
  int q00[4], rbB[4];
#pragma unroll
  for (int c = 0; c < 4; ++c) {
    int row = w * 32 + c * 8 + (l >> 3);
    int m = m0 + row;
    if (m > 26243) m = 26243;
    int b = m / 6561, p = m % 6561;
    int d1 = p / 729, r = p % 729;
    int d2 = r / 81;
    r %= 81;
    int d3 = r / 9, d4 = r % 9;
    q00[c] = b * 14641 + ((d1 * 11 + d2) * 11 + d3) * 11 + d4;
    rbB[c] = row * 128 + swz;
  }

  const int l15 = l & 15;
  const int klo = (l >> 4) << 4;
  const int sx = (l & 7) << 4;
  const int arow0 = (wm * 64 + l15) * 128;
  const int brow0 = 16384 + (wn * 64 + l15) * 128;

  f32x4 acc[4][4];
#pragma unroll
  for (int mi = 0; mi < 4; ++mi)
#pragma unroll
    for (int ni = 0; ni < 4; ++ni) acc[mi][ni] = (f32x4){0.f, 0.f, 0.f, 0.f};

  auto stage = [&](int t, int nb) {
    int j1 = t / 27, j2 = (t / 9) % 3, j3 = (t / 3) % 3, j4 = t % 3;
    int delta = ((j1 * 11 + j2) * 11 + j3) * 11 + j4;
#pragma unroll
    for (int c = 0; c < 4; ++c) {
      GLD16(xpB + (((size_t)(q00[c] + delta)) << 7) + swz,
            nb + w * 4096 + c * 1024);
      GLD16(wB + (((size_t)t) << 14) + rbB[c],
            nb + 16384 + w * 4096 + c * 1024);
    }
  };

  const int t0 = ky * 41;            // 0 or 41
  const int nt = 41 - ky;            // 41 or 40

  stage(t0, 0);

  for (int ti = 0; ti < nt; ++ti) {
    asm volatile("s_waitcnt vmcnt(0)" ::: "memory");
    __builtin_amdgcn_s_barrier();
    if (ti + 1 < nt) stage(t0 + ti + 1, ((ti + 1) & 1) * 32768);
    const char* sb = smem + (ti & 1) * 32768;
#pragma unroll
    for (int kh = 0; kh < 2; ++kh) {
      const int kx = ((kh << 6) + klo) ^ sx;
      bf16x8v af[4], bfr[4];
#pragma unroll
      for (int mi = 0; mi < 4; ++mi)
        af[mi] = *(const bf16x8v*)(sb + arow0 + mi * 2048 + kx);
#pragma unroll
      for (int ni = 0; ni < 4; ++ni)
        bfr[ni] = *(const bf16x8v*)(sb + brow0 + ni * 2048 + kx);
#pragma unroll
      for (int mi = 0; mi < 4; ++mi)
#pragma unroll
        for (int ni = 0; ni < 4; ++ni)
          acc[mi][ni] = __builtin_amdgcn_mfma_f32_16x16x32_bf16(
              af[mi], bfr[ni], acc[mi][ni], 0, 0, 0);
    }
  }

  __hip_bfloat16* pp = part + (size_t)ky * 3359232;
  const int prow = m0 + wm * 64 + ((l >> 4) << 2);
  const int col0 = wn * 64 + l15;
#pragma unroll
  for (int ni = 0; ni < 4; ++ni) {
    int cn = col0 + ni * 16;
#pragma unroll
    for (int mi = 0; mi < 4; ++mi)
#pragma unroll
      for (int j = 0; j < 4; ++j) {
        int m = prow + mi * 16 + j;
        if (m < 26244)
          pp[(size_t)m * 128 + cn] = __float2bfloat16(acc[mi][ni][j]);
      }
  }
}

// ---- L3+L4 fused (+L2 reduce fused into staging) ---------------------------
__global__ __launch_bounds__(512) void gemm_fused34(
    const __hip_bfloat16* __restrict__ p0, const __hip_bfloat16* __restrict__ p1,
    const __hip_bfloat16* __restrict__ w3, const __hip_bfloat16* __restrict__ w4,
    const float* __restrict__ b2r, const float* __restrict__ b2i,
    const float* __restrict__ b3r, const float* __restrict__ b3i,
    const float* __restrict__ b4r, const float* __restrict__ b4i,
    __hip_bfloat16* __restrict__ a4) {
  __shared__ __align__(128) char smem[98304];  // a2 tile 32KB | a3 tile 64KB
  const int tid = threadIdx.x, l = tid & 63, w = tid >> 6;
  const int wm = w & 1, wn = w >> 1;  // 2M x 4N
  const int pfix = blockIdx.x * 128;

  {
    int r = tid >> 2;
    int cb = (tid & 3) * 32;
    int m = pfix + r;
    if (m > 26243) m = 26243;
    const uint2* q0 = (const uint2*)(p0 + (size_t)m * 128 + cb);
    const uint2* q1 = (const uint2*)(p1 + (size_t)m * 128 + cb);
    __hip_bfloat16 tmp[32];
#pragma unroll
    for (int i = 0; i < 8; ++i) {
      uint2 ua = q0[i], ub = q1[i];
      const __hip_bfloat16* a = (const __hip_bfloat16*)&ua;
      const __hip_bfloat16* b = (const __hip_bfloat16*)&ub;
#pragma unroll
      for (int e = 0; e < 4; ++e) {
        int cn = cb + i * 4 + e;
        float bias = (cn < 64) ? b2r[cn] : b2i[cn - 64];
        float s = __bfloat162float(a[e]) + __bfloat162float(b[e]) + bias;
        tmp[i * 4 + e] = __float2bfloat16(fmaxf(s, 0.f));
      }
    }
    const int rs = (r & 7) << 4;
#pragma unroll
    for (int s4 = 0; s4 < 4; ++s4) {
      int col = cb * 2 + s4 * 16;
      *(uint4*)(smem + r * 256 + (col ^ rs)) = ((const uint4*)tmp)[s4];
    }
  }
  __syncthreads();

  const int l15 = l & 15;
  const int klo = (l >> 4) << 4;
  const int sx = (l & 7) << 4;

  f32x4 acc[4][4];
#pragma unroll
  for (int mi = 0; mi < 4; ++mi)
#pragma unroll
    for (int ni = 0; ni < 4; ++ni) acc[mi][ni] = (f32x4){0.f, 0.f, 0.f, 0.f};

  {
    const int arow3 = (wm * 64 + l15) * 256;
    const char* b3b = (const char*)w3 + (size_t)(wn * 64 + l15) * 256 + klo;
#pragma unroll
    for (int kh = 0; kh < 4; ++kh) {
      const int kx = ((kh << 6) + klo) ^ sx;
      bf16x8v af[4], bfr[4];
#pragma unroll
      for (int mi = 0; mi < 4; ++mi)
        af[mi] = *(const bf16x8v*)(smem + arow3 + mi * 4096 + kx);
#pragma unroll
      for (int ni = 0; ni < 4; ++ni)
        bfr[ni] = *(const bf16x8v*)(b3b + ni * 4096 + kh * 64);
#pragma unroll
      for (int mi = 0; mi < 4; ++mi)
#pragma unroll
        for (int ni = 0; ni < 4; ++ni)
          acc[mi][ni] = __builtin_amdgcn_mfma_f32_16x16x32_bf16(
              af[mi], bfr[ni], acc[mi][ni], 0, 0, 0);
    }
  }

  __syncthreads();
  {
    const int lrow = wm * 64 + ((l >> 4) << 2);
    const int col0 = wn * 64 + l15;
#pragma unroll
    for (int ni = 0; ni < 4; ++ni) {
      int cn = col0 + ni * 16;
      float bias = (cn < 128) ? b3r[cn] : b3i[cn - 128];
#pragma unroll
      for (int mi = 0; mi < 4; ++mi) {
        int row = lrow + mi * 16;
#pragma unroll
        for (int j = 0; j < 4; ++j) {
          float v = fmaxf(acc[mi][ni][j] + bias, 0.f);
          int addr = (32768 + (row + j) * 512 + cn * 2) ^ (((row + j) & 7) << 4);
          *(__hip_bfloat16*)(smem + addr) = __float2bfloat16(v);
        }
      }
    }
  }
  __syncthreads();

#pragma unroll
  for (int mi = 0; mi < 4; ++mi)
#pragma unroll
    for (int ni = 0; ni < 4; ++ni) acc[mi][ni] = (f32x4){0.f, 0.f, 0.f, 0.f};
  {
    const int arow4 = 32768 + (wm * 64 + l15) * 512;
    const char* b4b = (const char*)w4 + (size_t)(wn * 64 + l15) * 512 + klo;
#pragma unroll
    for (int kh = 0; kh < 8; ++kh) {
      const int kx = ((kh << 6) + klo) ^ sx;
      bf16x8v af[4], bfr[4];
#pragma unroll
      for (int mi = 0; mi < 4; ++mi)
        af[mi] = *(const bf16x8v*)(smem + arow4 + mi * 8192 + kx);
#pragma unroll
      for (int ni = 0; ni < 4; ++ni)
        bfr[ni] = *(const bf16x8v*)(b4b + ni * 8192 + kh * 64);
#pragma unroll
      for (int mi = 0; mi < 4; ++mi)
#pragma unroll
        for (int ni = 0; ni < 4; ++ni)
          acc[mi][ni] = __builtin_amdgcn_mfma_f32_16x16x32_bf16(
              af[mi], bfr[ni], acc[mi][ni], 0, 0, 0);
    }
  }

  {
    const int prow = pfix + wm * 64 + ((l >> 4) << 2);
    const int col0 = wn * 64 + l15;
#pragma unroll
    for (int ni = 0; ni < 4; ++ni) {
      int cn = col0 + ni * 16;
      float bias = (cn < 128) ? b4r[cn] : b4i[cn - 128];
#pragma unroll
      for (int mi = 0; mi < 4; ++mi)
#pragma unroll
        for (int j = 0; j < 4; ++j) {
          int m = prow + mi * 16 + j;
          if (m < 26244)
            a4[(size_t)m * 256 + cn] =
                __float2bfloat16(fmaxf(acc[mi][ni][j] + bias, 0.f));
        }
    }
  }
}

// ---- L5 GEMM ---------------------------------------------------------------
template <int K, int S2>
__global__ __launch_bounds__(512) void gemm_bg(
    const __hip_bfloat16* __restrict__ A, const __hip_bfloat16* __restrict__ Bm,
    const float* __restrict__ br, const float* __restrict__ bi,
    __hip_bfloat16* __restrict__ C, int M, int N, int Cout) {
  constexpr int ROWB = 2 * K;
  constexpr int NKH = K / 32;
  constexpr int LG = (K == 128) ? 8 : 9;
  __shared__ __align__(128) char smem[128 * ROWB];
  const int tid = threadIdx.x, l = tid & 63, w = tid >> 6;
  const int wm = w & 1, wn = w >> 1;
  const int p0 = blockIdx.x * 128, n0 = blockIdx.y * 128;

  const char* aB = (const char*)A;
#pragma unroll
  for (int g = 0; g < NKH; ++g) {
    int W = (w * NKH + g) * 1024 + (l << 4);
    int row = W >> LG;
    int cb = W & (ROWB - 1);
    int m = p0 + row;
    if (m >= M) m = M - 1;
    int srcrow;
    if (S2) {
      int bb_ = m / 625, r = m % 625;
      int d1 = r / 125;
      r %= 125;
      int d2 = r / 25;
      r %= 25;
      int d3 = r / 5, d4 = r % 5;
      srcrow = bb_ * 6561 + d1 * 1458 + d2 * 162 + d3 * 18 + d4 * 2;
    } else {
      srcrow = m;
    }
    GLD16(aB + (size_t)srcrow * ROWB + (cb ^ ((row & 7) << 4)), W);
  }
  asm volatile("s_waitcnt vmcnt(0)" ::: "memory");
  __syncthreads();

  const int l15 = l & 15;
  const int klo = (l >> 4) << 4;
  const int sx = (l & 7) << 4;
  const int arow0 = (wm * 64 + l15) * ROWB;
  const char* bb = (const char*)Bm + (size_t)(n0 + wn * 32 + l15) * ROWB + klo;

  f32x4 acc[4][2];
#pragma unroll
  for (int mi = 0; mi < 4; ++mi)
#pragma unroll
    for (int ni = 0; ni < 2; ++ni) acc[mi][ni] = (f32x4){0.f, 0.f, 0.f, 0.f};

#pragma unroll
  for (int kh = 0; kh < NKH; ++kh) {
    bf16x8v bfr[2];
#pragma unroll
    for (int ni = 0; ni < 2; ++ni)
      bfr[ni] = *(const bf16x8v*)(bb + ni * 16 * ROWB + kh * 64);
    const int kx = ((kh << 6) + klo) ^ sx;
    bf16x8v af[4];
#pragma unroll
    for (int mi = 0; mi < 4; ++mi)
      af[mi] = *(const bf16x8v*)(smem + arow0 + mi * 16 * ROWB + kx);
#pragma unroll
    for (int mi = 0; mi < 4; ++mi)
#pragma unroll
      for (int ni = 0; ni < 2; ++ni)
        acc[mi][ni] = __builtin_amdgcn_mfma_f32_16x16x32_bf16(
            af[mi], bfr[ni], acc[mi][ni], 0, 0, 0);
  }

  const int prow = p0 + wm * 64 + ((l >> 4) << 2);
  const int col0 = n0 + wn * 32 + l15;
#pragma unroll
  for (int ni = 0; ni < 2; ++ni) {
    int cn = col0 + ni * 16;
    float bias = (cn < Cout) ? br[cn] : bi[cn - Cout];
#pragma unroll
    for (int mi = 0; mi < 4; ++mi)
#pragma unroll
      for (int j = 0; j < 4; ++j) {
        int m = prow + mi * 16 + j;
        if (m < M)
          C[(size_t)m * N + cn] =
              __float2bfloat16(fmaxf(acc[mi][ni][j] + bias, 0.f));
      }
  }
}

// ---- FC --------------------------------------------------------------------
__global__ __launch_bounds__(256) void fc_kernel(
    const __hip_bfloat16* __restrict__ a5, const float* __restrict__ fcw,
    const float* __restrict__ fcb, float* __restrict__ out) {
  int bc = blockIdx.x * 4 + (threadIdx.x >> 6);
  int b = bc >> 6, c = bc & 63;
  int lane = threadIdx.x & 63;
  const __hip_bfloat16* base = a5 + (size_t)b * 625 * 128;
  float sr = 0.f, si = 0.f;
  for (int p = lane; p < 625; p += 64) {
    float wv = fcw[p];
    sr += __bfloat162float(base[(size_t)p * 128 + c]) * wv;
    si += __bfloat162float(base[(size_t)p * 128 + 64 + c]) * wv;
  }
#pragma unroll
  for (int s = 32; s > 0; s >>= 1) {
    sr += __shfl_down(sr, s);
    si += __shfl_down(si, s);
  }
  if (lane == 0) {
    out[bc] = sr + fcb[0];
    out[256 + bc] = si;
  }
}

extern "C" void kernel_launch(void* const* d_in, const int* in_sizes, int n_in,
                              void* d_out, int out_size, void* d_ws,
                              size_t ws_size, hipStream_t stream) {
  const float* xr = (const float*)d_in[0];
  const float* xi = (const float*)d_in[1];
  const float* w1r = (const float*)d_in[2];
  const float* w1i = (const float*)d_in[3];
  const float* b1r = (const float*)d_in[4];
  const float* b1i = (const float*)d_in[5];
  const float* w2r = (const float*)d_in[6];
  const float* w2i = (const float*)d_in[7];
  const float* b2r = (const float*)d_in[8];
  const float* b2i = (const float*)d_in[9];
  const float* w3r = (const float*)d_in[10];
  const float* w3i = (const float*)d_in[11];
  const float* b3r = (const float*)d_in[12];
  const float* b3i = (const float*)d_in[13];
  const float* w4r = (const float*)d_in[14];
  const float* w4i = (const float*)d_in[15];
  const float* b4r = (const float*)d_in[16];
  const float* b4i = (const float*)d_in[17];
  const float* w5r = (const float*)d_in[18];
  const float* w5i = (const float*)d_in[19];
  const float* b5r = (const float*)d_in[20];
  const float* b5i = (const float*)d_in[21];
  const float* fcw = (const float*)d_in[22];
  const float* fcb = (const float*)d_in[23];
  float* out = (float*)d_out;

  float* ws = (float*)d_ws;
  __hip_bfloat16* wt2b = (__hip_bfloat16*)(ws + 5184);     // 663552 bf16
  __hip_bfloat16* w3b = (__hip_bfloat16*)(ws + 336960);    // 32768 bf16
  __hip_bfloat16* w4b = (__hip_bfloat16*)(ws + 353344);    // 65536 bf16
  __hip_bfloat16* w5b = (__hip_bfloat16*)(ws + 386112);    // 32768 bf16
  __hip_bfloat16* xp = (__hip_bfloat16*)(ws + 402496);     // 3748096 bf16
  __hip_bfloat16* a4 = (__hip_bfloat16*)(ws + 3956160);    // 6718464 bf16
  __hip_bfloat16* a5 = (__hip_bfloat16*)(ws + 7315392);    // 320000 bf16
  __hip_bfloat16* w1b = (__hip_bfloat16*)(ws + 7475392);   // 16384 bf16
  // part: dedicated (fused34 reads it while writing a4)
  __hip_bfloat16* part = (__hip_bfloat16*)(ws + 7483584);  // 6718464 bf16
  // Aim aliases a4 region (dead until fused34; tail overruns into a5,
  // which is rewritten later by gemm_bg)
  __hip_bfloat16* Aim = (__hip_bfloat16*)(ws + 3956160);

  prep_fused<<<dim3(5410), 256, 0, stream>>>(
      xr, xi, w1r, w1i, w2r, w2i, w3r, w3i, w4r, w4i, w5r, w5i, w1b, wt2b,
      w3b, w4b, w5b, (uint4*)xp, Aim);

  gemm_l1<<<dim3(206), 512, 0, stream>>>(Aim, w1b, b1r, b1i, xp);
  cconv2_ksplit<<<dim3(206, 2), 256, 0, stream>>>(xp, wt2b, part);
  gemm_fused34<<<dim3(206), 512, 0, stream>>>(
      part, part + 3359232, w3b, w4b, b2r, b2i, b3r, b3i, b4r, b4i, a4);
  gemm_bg<256, 1><<<dim3(20, 1), 512, 0, stream>>>(a4, w5b, b5r, b5i, a5,
                                                   2500, 128, 64);
  fc_kernel<<<dim3(64), 256, 0, stream>>>(a5, fcw, fcb, out);
}

// Round 20
// 102.135 us; speedup vs baseline: 1.1758x; 1.0625x over previous
//
#include <hip/hip_runtime.h>
#include <hip/hip_bf16.h>

typedef __bf16 bf16x8v __attribute__((ext_vector_type(8)));
typedef float f32x4 __attribute__((ext_vector_type(4)));

#define GLD16(gp, loff)                                                     \
  __builtin_amdgcn_global_load_lds(                                         \
      (const __attribute__((address_space(1))) void*)(gp),                  \
      (__attribute__((address_space(3))) void*)(smem + (loff)), 16, 0, 0)

// ---------------------------------------------------------------------------
// Pipeline (r19 + fused34 M=64 TLP tile):
//  Aim  : [26244][256] bf16 im2col (aliases a4 region; dead until fused34).
//  xp   : [b][q:11^4][64] padded L1 out; prep zeroes ONLY halo rows.
//  part : 2 x [26244][128] bf16 L2 partials — dedicated region.
//  a4   : [26244][256] bf16;  a5 : [b*625][128] bf16
//  fused34: M-tile 64, LDS 48KB (a2 16K | a3 32K), grid 411, 8 waves 1Mx8N
//           -> ~1.6 blocks/CU TLP (was 98KB/1-block, 206 blocks underfill).
// ---------------------------------------------------------------------------

__global__ __launch_bounds__(256) void prep_fused(
    const float* __restrict__ xr, const float* __restrict__ xi,
    const float* __restrict__ w1r, const float* __restrict__ w1i,
    const float* __restrict__ w2r, const float* __restrict__ w2i,
    const float* __restrict__ w3r, const float* __restrict__ w3i,
    const float* __restrict__ w4r, const float* __restrict__ w4i,
    const float* __restrict__ w5r, const float* __restrict__ w5i,
    __hip_bfloat16* __restrict__ w1b, __hip_bfloat16* __restrict__ wt2b,
    __hip_bfloat16* __restrict__ w3b, __hip_bfloat16* __restrict__ w4b,
    __hip_bfloat16* __restrict__ w5b, uint4* __restrict__ xpz,
    __hip_bfloat16* __restrict__ Aim) {
  __shared__ uint lds[8192];  // im2col branch only (32 KB)
  const int bx = blockIdx.x;
  const int tid = threadIdx.x;
  auto pack11 = [](const float* wr, const float* wi, __hip_bfloat16* dst,
                   int Cout, int Cin, int idx) {
    int k2 = 2 * Cin;
    int k = idx % k2, n = idx / k2;
    int ci = (k < Cin) ? k : k - Cin;
    int co = (n < Cout) ? n : n - Cout;
    int widx = co * Cin + ci;
    float v;
    if (n < Cout) v = (k < Cin) ? wr[widx] : -wi[widx];
    else          v = (k < Cin) ? wi[widx] :  wr[widx];
    dst[idx] = __float2bfloat16(v);
  };
  if (bx < 1831) {                       // zero xp HALO rows only
    int i = bx * 256 + tid;
    if (i < 468512) {
      int q = (i >> 3) % 14641;
      unsigned e4 = q % 11;
      int r_ = q / 11;
      unsigned e3 = r_ % 11;
      r_ /= 11;
      unsigned e2 = r_ % 11;
      unsigned e1 = r_ / 11;
      bool interior = (e1 - 1u) < 9u && (e2 - 1u) < 9u && (e3 - 1u) < 9u &&
                      (e4 - 1u) < 9u;
      if (!interior) xpz[i] = make_uint4(0, 0, 0, 0);
    }
  } else if (bx < 4423) {                // wt2b taps 0..80: B[t][n:128][k:64]
    int idx = (bx - 1831) * 256 + tid;
    int k = idx & 63, n = (idx >> 6) & 127, t = idx >> 13;
    int ci = k & 31, kin_i = k >> 5;
    int co = n & 63, out_i = n >> 6;
    int widx = (co * 32 + ci) * 81 + t;
    float v;
    if (out_i == 0) v = (kin_i == 0) ? w2r[widx] : -w2i[widx];
    else            v = (kin_i == 0) ? w2i[widx] :  w2r[widx];
    wt2b[idx] = __float2bfloat16(v);
  } else if (bx < 4487) {                // w1b: [n:64][k:256]
    int idx = (bx - 4423) * 256 + tid;
    int n = idx >> 8, k = idx & 255;
    int t = k >> 1, c = k & 1, co = n & 31;
    float v = 0.f;
    if (t < 81) {
      if (n < 32) v = c ? -w1i[co * 81 + t] : w1r[co * 81 + t];
      else        v = c ?  w1r[co * 81 + t] : w1i[co * 81 + t];
    }
    w1b[idx] = __float2bfloat16(v);
  } else if (bx < 4615) {
    pack11(w3r, w3i, w3b, 128, 64, (bx - 4487) * 256 + tid);
  } else if (bx < 4871) {
    pack11(w4r, w4i, w4b, 128, 128, (bx - 4615) * 256 + tid);
  } else if (bx < 4999) {                // w5b: 128x256 = 128 blocks
    pack11(w5r, w5i, w5b, 64, 128, (bx - 4871) * 256 + tid);
  } else {                               // im2col: Aim[m][256] bf16
    const int row = tid & 63;
    const int tg = tid >> 6;
    const int m0 = (bx - 4999) * 64;
    int m = m0 + row;
    if (m > 26243) m = 26243;
    int b = m / 6561, p = m % 6561;
    int d1 = p / 729, r = p % 729;
    int d2 = r / 81;
    r %= 81;
    int d3 = r / 9, d4 = r % 9;
    const int base = b * 160000 + d1 * 16000 + d2 * 800 + d3 * 40 + d4 * 2;
    const int xorv = (row & 31) << 2;
    const int rbase = row << 7;

    const int tend = (tg == 3) ? 81 : tg * 21 + 21;
    for (int t = tg * 21; t < tend; ++t) {
      int j1 = t / 27, j2 = (t / 9) % 3, j3 = (t / 3) % 3, j4 = t % 3;
      int xo = base + j1 * 8000 + j2 * 400 + j3 * 20 + j4;
      __hip_bfloat16 h2[2] = {__float2bfloat16(xr[xo]),
                              __float2bfloat16(xi[xo])};
      lds[rbase + (t ^ xorv)] = *(const uint*)h2;
    }
    for (int t = 81 + tg; t < 128; t += 4) lds[rbase + (t ^ xorv)] = 0u;
    __syncthreads();

    uint4* dst = (uint4*)(Aim + (size_t)m0 * 256);
#pragma unroll
    for (int ph = 0; ph < 8; ++ph) {
      int W = ph * 4096 + tid * 16;
      int rw = W >> 9;
      int c4 = (W & 511) >> 2;
      int li = (rw << 7) + (c4 ^ ((rw & 31) << 2));
      uint4 v = {lds[li], lds[li + 1], lds[li + 2], lds[li + 3]};
      dst[W >> 4] = v;
    }
  }
}

// ---- L1 GEMM: M=26244, N=64, K=256. 8 waves 4Mx2N; LDS-staged epilogue. ----
__global__ __launch_bounds__(512) void gemm_l1(
    const __hip_bfloat16* __restrict__ Aim, const __hip_bfloat16* __restrict__ Bm,
    const float* __restrict__ br, const float* __restrict__ bi,
    __hip_bfloat16* __restrict__ xp) {
  __shared__ __align__(128) char smem[65536];  // 128 rows x 512 B
  const int tid = threadIdx.x, l = tid & 63, w = tid >> 6;
  const int wm = w & 3, wn = w >> 2;  // 4M x 2N
  const int p0 = blockIdx.x * 128;

  const char* aB = (const char*)Aim;
#pragma unroll
  for (int g = 0; g < 8; ++g) {
    int W = (w * 8 + g) * 1024 + (l << 4);
    int row = W >> 9;
    int cb = W & 511;
    int m = p0 + row;
    if (m > 26243) m = 26243;
    GLD16(aB + (size_t)m * 512 + (cb ^ ((row & 7) << 4)), W);
  }
  asm volatile("s_waitcnt vmcnt(0)" ::: "memory");
  __syncthreads();

  const int l15 = l & 15;
  const int klo = (l >> 4) << 4;
  const int sx = (l & 7) << 4;
  const int arow0 = (wm * 32 + l15) * 512;
  const char* bb = (const char*)Bm + (size_t)(wn * 32 + l15) * 512 + klo;

  f32x4 acc[2][2];
#pragma unroll
  for (int mi = 0; mi < 2; ++mi)
#pragma unroll
    for (int ni = 0; ni < 2; ++ni) acc[mi][ni] = (f32x4){0.f, 0.f, 0.f, 0.f};

#pragma unroll
  for (int kh = 0; kh < 8; ++kh) {
    bf16x8v bfr[2];
#pragma unroll
    for (int ni = 0; ni < 2; ++ni)
      bfr[ni] = *(const bf16x8v*)(bb + ni * 16 * 512 + kh * 64);
    const int kx = ((kh << 6) + klo) ^ sx;
    bf16x8v af[2];
#pragma unroll
    for (int mi = 0; mi < 2; ++mi)
      af[mi] = *(const bf16x8v*)(smem + arow0 + mi * 8192 + kx);
#pragma unroll
    for (int mi = 0; mi < 2; ++mi)
#pragma unroll
      for (int ni = 0; ni < 2; ++ni)
        acc[mi][ni] = __builtin_amdgcn_mfma_f32_16x16x32_bf16(
            af[mi], bfr[ni], acc[mi][ni], 0, 0, 0);
  }

  __syncthreads();  // A-tile reads complete; reuse smem
  {
    const int lrow0 = wm * 32 + ((l >> 4) << 2);
    const int ch0 = wn * 32 + l15;
#pragma unroll
    for (int ni = 0; ni < 2; ++ni) {
      int ch = ch0 + ni * 16;
      float bias = (ch < 32) ? br[ch] : bi[ch - 32];
#pragma unroll
      for (int mi = 0; mi < 2; ++mi)
#pragma unroll
        for (int j = 0; j < 4; ++j) {
          int row = lrow0 + mi * 16 + j;
          int byteoff =
              row * 128 + ((((ch >> 3) ^ (row & 7)) << 4)) + (ch & 7) * 2;
          *(__hip_bfloat16*)(smem + byteoff) =
              __float2bfloat16(fmaxf(acc[mi][ni][j] + bias, 0.f));
        }
    }
  }
  __syncthreads();
#pragma unroll
  for (int it = 0; it < 2; ++it) {
    int W = it * 8192 + tid * 16;
    int row = W >> 7;
    int slot = (W & 127) >> 4;
    int m = p0 + row;
    if (m < 26244) {
      uint4 v = *(const uint4*)(smem + row * 128 + ((slot ^ (row & 7)) << 4));
      int b = m / 6561, p = m % 6561;
      int d1 = p / 729, r = p % 729;
      int d2 = r / 81;
      r %= 81;
      int d3 = r / 9, d4 = r % 9;
      int q = (((d1 + 1) * 11 + (d2 + 1)) * 11 + (d3 + 1)) * 11 + (d4 + 1);
      *(uint4*)(xp + ((size_t)(b * 14641 + q)) * 64 + slot * 8) = v;
    }
  }
}

// ---- Layer 2: r13-proven. K-split grid (206,2); 4 waves 2Mx2N (64x64). ----
__global__ __launch_bounds__(256) void cconv2_ksplit(
    const __hip_bfloat16* __restrict__ xp, const __hip_bfloat16* __restrict__ wb,
    __hip_bfloat16* __restrict__ part) {
  __shared__ __align__(128) char smem[65536];  // 2 x (A 16KB | B 16KB)
  const int tid = threadIdx.x;
  const int l = tid & 63, w = tid >> 6;        // 4 waves
  const int wm = w & 1, wn = w >> 1;           // 2M x 2N, wave tile 64x64
  const int m0 = blockIdx.x * 128;
  const int ky = blockIdx.y;                   // K-half: taps [0,41) / [41,81)

  const int swz = ((l & 7) ^ (l >> 3)) << 4;
  const char* xpB = (const char*)xp;
  const char* wB = (const char*)wb;
  int q00[4], rbB[4];
#pragma unroll
  for (int c = 0; c < 4; ++c) {
    int row = w * 32 + c * 8 + (l >> 3);
    int m = m0 + row;
    if (m > 26243) m = 26243;
    int b = m / 6561, p = m % 6561;
    int d1 = p / 729, r = p % 729;
    int d2 = r / 81;
    r %= 81;
    int d3 = r / 9, d4 = r % 9;
    q00[c] = b * 14641 + ((d1 * 11 + d2) * 11 + d3) * 11 + d4;
    rbB[c] = row * 128 + swz;
  }

  const int l15 = l & 15;
  const int klo = (l >> 4) << 4;
  const int sx = (l & 7) << 4;
  const int arow0 = (wm * 64 + l15) * 128;
  const int brow0 = 16384 + (wn * 64 + l15) * 128;

  f32x4 acc[4][4];
#pragma unroll
  for (int mi = 0; mi < 4; ++mi)
#pragma unroll
    for (int ni = 0; ni < 4; ++ni) acc[mi][ni] = (f32x4){0.f, 0.f, 0.f, 0.f};

  auto stage = [&](int t, int nb) {
    int j1 = t / 27, j2 = (t / 9) % 3, j3 = (t / 3) % 3, j4 = t % 3;
    int delta = ((j1 * 11 + j2) * 11 + j3) * 11 + j4;
#pragma unroll
    for (int c = 0; c < 4; ++c) {
      GLD16(xpB + (((size_t)(q00[c] + delta)) << 7) + swz,
            nb + w * 4096 + c * 1024);
      GLD16(wB + (((size_t)t) << 14) + rbB[c],
            nb + 16384 + w * 4096 + c * 1024);
    }
  };

  const int t0 = ky * 41;            // 0 or 41
  const int nt = 41 - ky;            // 41 or 40

  stage(t0, 0);

  for (int ti = 0; ti < nt; ++ti) {
    asm volatile("s_waitcnt vmcnt(0)" ::: "memory");
    __builtin_amdgcn_s_barrier();
    if (ti + 1 < nt) stage(t0 + ti + 1, ((ti + 1) & 1) * 32768);
    const char* sb = smem + (ti & 1) * 32768;
#pragma unroll
    for (int kh = 0; kh < 2; ++kh) {
      const int kx = ((kh << 6) + klo) ^ sx;
      bf16x8v af[4], bfr[4];
#pragma unroll
      for (int mi = 0; mi < 4; ++mi)
        af[mi] = *(const bf16x8v*)(sb + arow0 + mi * 2048 + kx);
#pragma unroll
      for (int ni = 0; ni < 4; ++ni)
        bfr[ni] = *(const bf16x8v*)(sb + brow0 + ni * 2048 + kx);
#pragma unroll
      for (int mi = 0; mi < 4; ++mi)
#pragma unroll
        for (int ni = 0; ni < 4; ++ni)
          acc[mi][ni] = __builtin_amdgcn_mfma_f32_16x16x32_bf16(
              af[mi], bfr[ni], acc[mi][ni], 0, 0, 0);
    }
  }

  __hip_bfloat16* pp = part + (size_t)ky * 3359232;
  const int prow = m0 + wm * 64 + ((l >> 4) << 2);
  const int col0 = wn * 64 + l15;
#pragma unroll
  for (int ni = 0; ni < 4; ++ni) {
    int cn = col0 + ni * 16;
#pragma unroll
    for (int mi = 0; mi < 4; ++mi)
#pragma unroll
      for (int j = 0; j < 4; ++j) {
        int m = prow + mi * 16 + j;
        if (m < 26244)
          pp[(size_t)m * 128 + cn] = __float2bfloat16(acc[mi][ni][j]);
      }
  }
}

// ---- L3+L4 fused, M=64 tile (48KB LDS -> TLP). 8 waves 1Mx8N. --------------
__global__ __launch_bounds__(512) void gemm_fused34(
    const __hip_bfloat16* __restrict__ p0, const __hip_bfloat16* __restrict__ p1,
    const __hip_bfloat16* __restrict__ w3, const __hip_bfloat16* __restrict__ w4,
    const float* __restrict__ b2r, const float* __restrict__ b2i,
    const float* __restrict__ b3r, const float* __restrict__ b3i,
    const float* __restrict__ b4r, const float* __restrict__ b4i,
    __hip_bfloat16* __restrict__ a4) {
  __shared__ __align__(128) char smem[49152];  // a2 16KB | a3 32KB @16384
  const int tid = threadIdx.x, l = tid & 63, w = tid >> 6;
  const int wn = w;  // 1M x 8N, wave tile 64x32
  const int m0 = blockIdx.x * 64;

  // ---- stage a2 tile [64 rows][128 ch] from partials + bias2 + relu -------
  {
    int r = tid >> 3;                // 0..63
    int cb = (tid & 7) * 16;         // 16 ch per thread
    int m = m0 + r;
    if (m > 26243) m = 26243;
    const uint2* q0 = (const uint2*)(p0 + (size_t)m * 128 + cb);
    const uint2* q1 = (const uint2*)(p1 + (size_t)m * 128 + cb);
    __hip_bfloat16 tmp[16];
#pragma unroll
    for (int i = 0; i < 4; ++i) {
      uint2 ua = q0[i], ub = q1[i];
      const __hip_bfloat16* a = (const __hip_bfloat16*)&ua;
      const __hip_bfloat16* b = (const __hip_bfloat16*)&ub;
#pragma unroll
      for (int e = 0; e < 4; ++e) {
        int cn = cb + i * 4 + e;
        float bias = (cn < 64) ? b2r[cn] : b2i[cn - 64];
        float s = __bfloat162float(a[e]) + __bfloat162float(b[e]) + bias;
        tmp[i * 4 + e] = __float2bfloat16(fmaxf(s, 0.f));
      }
    }
    const int rs = (r & 7) << 4;
#pragma unroll
    for (int s4 = 0; s4 < 2; ++s4) {
      int col = cb * 2 + s4 * 16;    // byte col within 256B row
      *(uint4*)(smem + r * 256 + (col ^ rs)) = ((const uint4*)tmp)[s4];
    }
  }
  __syncthreads();

  const int l15 = l & 15;
  const int klo = (l >> 4) << 4;
  const int sx = (l & 7) << 4;

  f32x4 acc[4][2];
#pragma unroll
  for (int mi = 0; mi < 4; ++mi)
#pragma unroll
    for (int ni = 0; ni < 2; ++ni) acc[mi][ni] = (f32x4){0.f, 0.f, 0.f, 0.f};

  // ---- L3: K=128 (4 kh), A rows = mi*16+l15, B3 cols = wn*32+ni*16+l15 ----
  {
    const int arow3 = l15 * 256;
    const char* b3b = (const char*)w3 + (size_t)(wn * 32 + l15) * 256 + klo;
#pragma unroll
    for (int kh = 0; kh < 4; ++kh) {
      const int kx = ((kh << 6) + klo) ^ sx;
      bf16x8v af[4], bfr[2];
#pragma unroll
      for (int mi = 0; mi < 4; ++mi)
        af[mi] = *(const bf16x8v*)(smem + arow3 + mi * 4096 + kx);
#pragma unroll
      for (int ni = 0; ni < 2; ++ni)
        bfr[ni] = *(const bf16x8v*)(b3b + ni * 4096 + kh * 64);
#pragma unroll
      for (int mi = 0; mi < 4; ++mi)
#pragma unroll
        for (int ni = 0; ni < 2; ++ni)
          acc[mi][ni] = __builtin_amdgcn_mfma_f32_16x16x32_bf16(
              af[mi], bfr[ni], acc[mi][ni], 0, 0, 0);
    }
  }

  // a3 tile write @16384: [64 rows][512B], row-XOR swizzle. a3 region is
  // disjoint from a2 tile, so only one barrier (write->read) needed.
  {
    const int lrow = (l >> 4) << 2;
    const int col0 = wn * 32 + l15;
#pragma unroll
    for (int ni = 0; ni < 2; ++ni) {
      int cn = col0 + ni * 16;
      float bias = (cn < 128) ? b3r[cn] : b3i[cn - 128];
#pragma unroll
      for (int mi = 0; mi < 4; ++mi) {
        int row = lrow + mi * 16;
#pragma unroll
        for (int j = 0; j < 4; ++j) {
          float v = fmaxf(acc[mi][ni][j] + bias, 0.f);
          int addr = (16384 + (row + j) * 512 + cn * 2) ^ (((row + j) & 7) << 4);
          *(__hip_bfloat16*)(smem + addr) = __float2bfloat16(v);
        }
      }
    }
  }
  __syncthreads();

  // ---- L4: K=256 (8 kh), A from a3 tile @16384, B4 from global ------------
#pragma unroll
  for (int mi = 0; mi < 4; ++mi)
#pragma unroll
    for (int ni = 0; ni < 2; ++ni) acc[mi][ni] = (f32x4){0.f, 0.f, 0.f, 0.f};
  {
    const int arow4 = 16384 + l15 * 512;
    const char* b4b = (const char*)w4 + (size_t)(wn * 32 + l15) * 512 + klo;
#pragma unroll
    for (int kh = 0; kh < 8; ++kh) {
      const int kx = ((kh << 6) + klo) ^ sx;
      bf16x8v af[4], bfr[2];
#pragma unroll
      for (int mi = 0; mi < 4; ++mi)
        af[mi] = *(const bf16x8v*)(smem + arow4 + mi * 8192 + kx);
#pragma unroll
      for (int ni = 0; ni < 2; ++ni)
        bfr[ni] = *(const bf16x8v*)(b4b + ni * 8192 + kh * 64);
#pragma unroll
      for (int mi = 0; mi < 4; ++mi)
#pragma unroll
        for (int ni = 0; ni < 2; ++ni)
          acc[mi][ni] = __builtin_amdgcn_mfma_f32_16x16x32_bf16(
              af[mi], bfr[ni], acc[mi][ni], 0, 0, 0);
    }
  }

  {
    const int prow = m0 + ((l >> 4) << 2);
    const int col0 = wn * 32 + l15;
#pragma unroll
    for (int ni = 0; ni < 2; ++ni) {
      int cn = col0 + ni * 16;
      float bias = (cn < 128) ? b4r[cn] : b4i[cn - 128];
#pragma unroll
      for (int mi = 0; mi < 4; ++mi)
#pragma unroll
        for (int j = 0; j < 4; ++j) {
          int m = prow + mi * 16 + j;
          if (m < 26244)
            a4[(size_t)m * 256 + cn] =
                __float2bfloat16(fmaxf(acc[mi][ni][j] + bias, 0.f));
        }
    }
  }
}

// ---- L5 GEMM ---------------------------------------------------------------
template <int K, int S2>
__global__ __launch_bounds__(512) void gemm_bg(
    const __hip_bfloat16* __restrict__ A, const __hip_bfloat16* __restrict__ Bm,
    const float* __restrict__ br, const float* __restrict__ bi,
    __hip_bfloat16* __restrict__ C, int M, int N, int Cout) {
  constexpr int ROWB = 2 * K;
  constexpr int NKH = K / 32;
  constexpr int LG = (K == 128) ? 8 : 9;
  __shared__ __align__(128) char smem[128 * ROWB];
  const int tid = threadIdx.x, l = tid & 63, w = tid >> 6;
  const int wm = w & 1, wn = w >> 1;
  const int p0 = blockIdx.x * 128, n0 = blockIdx.y * 128;

  const char* aB = (const char*)A;
#pragma unroll
  for (int g = 0; g < NKH; ++g) {
    int W = (w * NKH + g) * 1024 + (l << 4);
    int row = W >> LG;
    int cb = W & (ROWB - 1);
    int m = p0 + row;
    if (m >= M) m = M - 1;
    int srcrow;
    if (S2) {
      int bb_ = m / 625, r = m % 625;
      int d1 = r / 125;
      r %= 125;
      int d2 = r / 25;
      r %= 25;
      int d3 = r / 5, d4 = r % 5;
      srcrow = bb_ * 6561 + d1 * 1458 + d2 * 162 + d3 * 18 + d4 * 2;
    } else {
      srcrow = m;
    }
    GLD16(aB + (size_t)srcrow * ROWB + (cb ^ ((row & 7) << 4)), W);
  }
  asm volatile("s_waitcnt vmcnt(0)" ::: "memory");
  __syncthreads();

  const int l15 = l & 15;
  const int klo = (l >> 4) << 4;
  const int sx = (l & 7) << 4;
  const int arow0 = (wm * 64 + l15) * ROWB;
  const char* bb = (const char*)Bm + (size_t)(n0 + wn * 32 + l15) * ROWB + klo;

  f32x4 acc[4][2];
#pragma unroll
  for (int mi = 0; mi < 4; ++mi)
#pragma unroll
    for (int ni = 0; ni < 2; ++ni) acc[mi][ni] = (f32x4){0.f, 0.f, 0.f, 0.f};

#pragma unroll
  for (int kh = 0; kh < NKH; ++kh) {
    bf16x8v bfr[2];
#pragma unroll
    for (int ni = 0; ni < 2; ++ni)
      bfr[ni] = *(const bf16x8v*)(bb + ni * 16 * ROWB + kh * 64);
    const int kx = ((kh << 6) + klo) ^ sx;
    bf16x8v af[4];
#pragma unroll
    for (int mi = 0; mi < 4; ++mi)
      af[mi] = *(const bf16x8v*)(smem + arow0 + mi * 16 * ROWB + kx);
#pragma unroll
    for (int mi = 0; mi < 4; ++mi)
#pragma unroll
      for (int ni = 0; ni < 2; ++ni)
        acc[mi][ni] = __builtin_amdgcn_mfma_f32_16x16x32_bf16(
            af[mi], bfr[ni], acc[mi][ni], 0, 0, 0);
  }

  const int prow = p0 + wm * 64 + ((l >> 4) << 2);
  const int col0 = n0 + wn * 32 + l15;
#pragma unroll
  for (int ni = 0; ni < 2; ++ni) {
    int cn = col0 + ni * 16;
    float bias = (cn < Cout) ? br[cn] : bi[cn - Cout];
#pragma unroll
    for (int mi = 0; mi < 4; ++mi)
#pragma unroll
      for (int j = 0; j < 4; ++j) {
        int m = prow + mi * 16 + j;
        if (m < M)
          C[(size_t)m * N + cn] =
              __float2bfloat16(fmaxf(acc[mi][ni][j] + bias, 0.f));
      }
  }
}

// ---- FC --------------------------------------------------------------------
__global__ __launch_bounds__(256) void fc_kernel(
    const __hip_bfloat16* __restrict__ a5, const float* __restrict__ fcw,
    const float* __restrict__ fcb, float* __restrict__ out) {
  int bc = blockIdx.x * 4 + (threadIdx.x >> 6);
  int b = bc >> 6, c = bc & 63;
  int lane = threadIdx.x & 63;
  const __hip_bfloat16* base = a5 + (size_t)b * 625 * 128;
  float sr = 0.f, si = 0.f;
  for (int p = lane; p < 625; p += 64) {
    float wv = fcw[p];
    sr += __bfloat162float(base[(size_t)p * 128 + c]) * wv;
    si += __bfloat162float(base[(size_t)p * 128 + 64 + c]) * wv;
  }
#pragma unroll
  for (int s = 32; s > 0; s >>= 1) {
    sr += __shfl_down(sr, s);
    si += __shfl_down(si, s);
  }
  if (lane == 0) {
    out[bc] = sr + fcb[0];
    out[256 + bc] = si;
  }
}

extern "C" void kernel_launch(void* const* d_in, const int* in_sizes, int n_in,
                              void* d_out, int out_size, void* d_ws,
                              size_t ws_size, hipStream_t stream) {
  const float* xr = (const float*)d_in[0];
  const float* xi = (const float*)d_in[1];
  const float* w1r = (const float*)d_in[2];
  const float* w1i = (const float*)d_in[3];
  const float* b1r = (const float*)d_in[4];
  const float* b1i = (const float*)d_in[5];
  const float* w2r = (const float*)d_in[6];
  const float* w2i = (const float*)d_in[7];
  const float* b2r = (const float*)d_in[8];
  const float* b2i = (const float*)d_in[9];
  const float* w3r = (const float*)d_in[10];
  const float* w3i = (const float*)d_in[11];
  const float* b3r = (const float*)d_in[12];
  const float* b3i = (const float*)d_in[13];
  const float* w4r = (const float*)d_in[14];
  const float* w4i = (const float*)d_in[15];
  const float* b4r = (const float*)d_in[16];
  const float* b4i = (const float*)d_in[17];
  const float* w5r = (const float*)d_in[18];
  const float* w5i = (const float*)d_in[19];
  const float* b5r = (const float*)d_in[20];
  const float* b5i = (const float*)d_in[21];
  const float* fcw = (const float*)d_in[22];
  const float* fcb = (const float*)d_in[23];
  float* out = (float*)d_out;

  float* ws = (float*)d_ws;
  __hip_bfloat16* wt2b = (__hip_bfloat16*)(ws + 5184);     // 663552 bf16
  __hip_bfloat16* w3b = (__hip_bfloat16*)(ws + 336960);    // 32768 bf16
  __hip_bfloat16* w4b = (__hip_bfloat16*)(ws + 353344);    // 65536 bf16
  __hip_bfloat16* w5b = (__hip_bfloat16*)(ws + 386112);    // 32768 bf16
  __hip_bfloat16* xp = (__hip_bfloat16*)(ws + 402496);     // 3748096 bf16
  __hip_bfloat16* a4 = (__hip_bfloat16*)(ws + 3956160);    // 6718464 bf16
  __hip_bfloat16* a5 = (__hip_bfloat16*)(ws + 7315392);    // 320000 bf16
  __hip_bfloat16* w1b = (__hip_bfloat16*)(ws + 7475392);   // 16384 bf16
  // part: dedicated (fused34 reads it while writing a4)
  __hip_bfloat16* part = (__hip_bfloat16*)(ws + 7483584);  // 6718464 bf16
  // Aim aliases a4 region (dead until fused34; tail overruns into a5,
  // which is rewritten later by gemm_bg)
  __hip_bfloat16* Aim = (__hip_bfloat16*)(ws + 3956160);

  prep_fused<<<dim3(5410), 256, 0, stream>>>(
      xr, xi, w1r, w1i, w2r, w2i, w3r, w3i, w4r, w4i, w5r, w5i, w1b, wt2b,
      w3b, w4b, w5b, (uint4*)xp, Aim);

  gemm_l1<<<dim3(206), 512, 0, stream>>>(Aim, w1b, b1r, b1i, xp);
  cconv2_ksplit<<<dim3(206, 2), 256, 0, stream>>>(xp, wt2b, part);
  gemm_fused34<<<dim3(411), 512, 0, stream>>>(
      part, part + 3359232, w3b, w4b, b2r, b2i, b3r, b3i, b4r, b4i, a4);
  gemm_bg<256, 1><<<dim3(20, 1), 512, 0, stream>>>(a4, w5b, b5r, b5i, a5,
                                                   2500, 128, 64);
  fc_kernel<<<dim3(64), 256, 0, stream>>>(a5, fcw, fcb, out);
}

// Round 21
// 100.602 us; speedup vs baseline: 1.1937x; 1.0152x over previous
//
#include <hip/hip_runtime.h>
#include <hip/hip_bf16.h>

typedef __bf16 bf16x8v __attribute__((ext_vector_type(8)));
typedef float f32x4 __attribute__((ext_vector_type(4)));

#define GLD16(gp, loff)                                                     \
  __builtin_amdgcn_global_load_lds(                                         \
      (const __attribute__((address_space(1))) void*)(gp),                  \
      (__attribute__((address_space(3))) void*)(smem + (loff)), 16, 0, 0)

// ---------------------------------------------------------------------------
// Pipeline (r20 + cconv2 XCD pair-major swizzle):
//  Aim  : [26244][256] bf16 im2col (aliases a4 region; dead until fused34).
//  xp   : [b][q:11^4][64] padded L1 out; prep zeroes ONLY halo rows.
//  part : 2 x [26244][128] bf16 L2 partials — dedicated region.
//  a4   : [26244][256] bf16;  a5 : [b*625][128] bf16
//  cconv2: flat grid 412, pair-major XCD-chunked swizzle — both K-halves of
//          an M-tile share an XCD (xp row overlap -> L2 reuse).
// ---------------------------------------------------------------------------

__global__ __launch_bounds__(256) void prep_fused(
    const float* __restrict__ xr, const float* __restrict__ xi,
    const float* __restrict__ w1r, const float* __restrict__ w1i,
    const float* __restrict__ w2r, const float* __restrict__ w2i,
    const float* __restrict__ w3r, const float* __restrict__ w3i,
    const float* __restrict__ w4r, const float* __restrict__ w4i,
    const float* __restrict__ w5r, const float* __restrict__ w5i,
    __hip_bfloat16* __restrict__ w1b, __hip_bfloat16* __restrict__ wt2b,
    __hip_bfloat16* __restrict__ w3b, __hip_bfloat16* __restrict__ w4b,
    __hip_bfloat16* __restrict__ w5b, uint4* __restrict__ xpz,
    __hip_bfloat16* __restrict__ Aim) {
  __shared__ uint lds[8192];  // im2col branch only (32 KB)
  const int bx = blockIdx.x;
  const int tid = threadIdx.x;
  auto pack11 = [](const float* wr, const float* wi, __hip_bfloat16* dst,
                   int Cout, int Cin, int idx) {
    int k2 = 2 * Cin;
    int k = idx % k2, n = idx / k2;
    int ci = (k < Cin) ? k : k - Cin;
    int co = (n < Cout) ? n : n - Cout;
    int widx = co * Cin + ci;
    float v;
    if (n < Cout) v = (k < Cin) ? wr[widx] : -wi[widx];
    else          v = (k < Cin) ? wi[widx] :  wr[widx];
    dst[idx] = __float2bfloat16(v);
  };
  if (bx < 1831) {                       // zero xp HALO rows only
    int i = bx * 256 + tid;
    if (i < 468512) {
      int q = (i >> 3) % 14641;
      unsigned e4 = q % 11;
      int r_ = q / 11;
      unsigned e3 = r_ % 11;
      r_ /= 11;
      unsigned e2 = r_ % 11;
      unsigned e1 = r_ / 11;
      bool interior = (e1 - 1u) < 9u && (e2 - 1u) < 9u && (e3 - 1u) < 9u &&
                      (e4 - 1u) < 9u;
      if (!interior) xpz[i] = make_uint4(0, 0, 0, 0);
    }
  } else if (bx < 4423) {                // wt2b taps 0..80: B[t][n:128][k:64]
    int idx = (bx - 1831) * 256 + tid;
    int k = idx & 63, n = (idx >> 6) & 127, t = idx >> 13;
    int ci = k & 31, kin_i = k >> 5;
    int co = n & 63, out_i = n >> 6;
    int widx = (co * 32 + ci) * 81 + t;
    float v;
    if (out_i == 0) v = (kin_i == 0) ? w2r[widx] : -w2i[widx];
    else            v = (kin_i == 0) ? w2i[widx] :  w2r[widx];
    wt2b[idx] = __float2bfloat16(v);
  } else if (bx < 4487) {                // w1b: [n:64][k:256]
    int idx = (bx - 4423) * 256 + tid;
    int n = idx >> 8, k = idx & 255;
    int t = k >> 1, c = k & 1, co = n & 31;
    float v = 0.f;
    if (t < 81) {
      if (n < 32) v = c ? -w1i[co * 81 + t] : w1r[co * 81 + t];
      else        v = c ?  w1r[co * 81 + t] : w1i[co * 81 + t];
    }
    w1b[idx] = __float2bfloat16(v);
  } else if (bx < 4615) {
    pack11(w3r, w3i, w3b, 128, 64, (bx - 4487) * 256 + tid);
  } else if (bx < 4871) {
    pack11(w4r, w4i, w4b, 128, 128, (bx - 4615) * 256 + tid);
  } else if (bx < 4999) {                // w5b: 128x256 = 128 blocks
    pack11(w5r, w5i, w5b, 64, 128, (bx - 4871) * 256 + tid);
  } else {                               // im2col: Aim[m][256] bf16
    const int row = tid & 63;
    const int tg = tid >> 6;
    const int m0 = (bx - 4999) * 64;
    int m = m0 + row;
    if (m > 26243) m = 26243;
    int b = m / 6561, p = m % 6561;
    int d1 = p / 729, r = p % 729;
    int d2 = r / 81;
    r %= 81;
    int d3 = r / 9, d4 = r % 9;
    const int base = b * 160000 + d1 * 16000 + d2 * 800 + d3 * 40 + d4 * 2;
    const int xorv = (row & 31) << 2;
    const int rbase = row << 7;

    const int tend = (tg == 3) ? 81 : tg * 21 + 21;
    for (int t = tg * 21; t < tend; ++t) {
      int j1 = t / 27, j2 = (t / 9) % 3, j3 = (t / 3) % 3, j4 = t % 3;
      int xo = base + j1 * 8000 + j2 * 400 + j3 * 20 + j4;
      __hip_bfloat16 h2[2] = {__float2bfloat16(xr[xo]),
                              __float2bfloat16(xi[xo])};
      lds[rbase + (t ^ xorv)] = *(const uint*)h2;
    }
    for (int t = 81 + tg; t < 128; t += 4) lds[rbase + (t ^ xorv)] = 0u;
    __syncthreads();

    uint4* dst = (uint4*)(Aim + (size_t)m0 * 256);
#pragma unroll
    for (int ph = 0; ph < 8; ++ph) {
      int W = ph * 4096 + tid * 16;
      int rw = W >> 9;
      int c4 = (W & 511) >> 2;
      int li = (rw << 7) + (c4 ^ ((rw & 31) << 2));
      uint4 v = {lds[li], lds[li + 1], lds[li + 2], lds[li + 3]};
      dst[W >> 4] = v;
    }
  }
}

// ---- L1 GEMM: M=26244, N=64, K=256. 8 waves 4Mx2N; LDS-staged epilogue. ----
__global__ __launch_bounds__(512) void gemm_l1(
    const __hip_bfloat16* __restrict__ Aim, const __hip_bfloat16* __restrict__ Bm,
    const float* __restrict__ br, const float* __restrict__ bi,
    __hip_bfloat16* __restrict__ xp) {
  __shared__ __align__(128) char smem[65536];  // 128 rows x 512 B
  const int tid = threadIdx.x, l = tid & 63, w = tid >> 6;
  const int wm = w & 3, wn = w >> 2;  // 4M x 2N
  const int p0 = blockIdx.x * 128;

  const char* aB = (const char*)Aim;
#pragma unroll
  for (int g = 0; g < 8; ++g) {
    int W = (w * 8 + g) * 1024 + (l << 4);
    int row = W >> 9;
    int cb = W & 511;
    int m = p0 + row;
    if (m > 26243) m = 26243;
    GLD16(aB + (size_t)m * 512 + (cb ^ ((row & 7) << 4)), W);
  }
  asm volatile("s_waitcnt vmcnt(0)" ::: "memory");
  __syncthreads();

  const int l15 = l & 15;
  const int klo = (l >> 4) << 4;
  const int sx = (l & 7) << 4;
  const int arow0 = (wm * 32 + l15) * 512;
  const char* bb = (const char*)Bm + (size_t)(wn * 32 + l15) * 512 + klo;

  f32x4 acc[2][2];
#pragma unroll
  for (int mi = 0; mi < 2; ++mi)
#pragma unroll
    for (int ni = 0; ni < 2; ++ni) acc[mi][ni] = (f32x4){0.f, 0.f, 0.f, 0.f};

#pragma unroll
  for (int kh = 0; kh < 8; ++kh) {
    bf16x8v bfr[2];
#pragma unroll
    for (int ni = 0; ni < 2; ++ni)
      bfr[ni] = *(const bf16x8v*)(bb + ni * 16 * 512 + kh * 64);
    const int kx = ((kh << 6) + klo) ^ sx;
    bf16x8v af[2];
#pragma unroll
    for (int mi = 0; mi < 2; ++mi)
      af[mi] = *(const bf16x8v*)(smem + arow0 + mi * 8192 + kx);
#pragma unroll
    for (int mi = 0; mi < 2; ++mi)
#pragma unroll
      for (int ni = 0; ni < 2; ++ni)
        acc[mi][ni] = __builtin_amdgcn_mfma_f32_16x16x32_bf16(
            af[mi], bfr[ni], acc[mi][ni], 0, 0, 0);
  }

  __syncthreads();  // A-tile reads complete; reuse smem
  {
    const int lrow0 = wm * 32 + ((l >> 4) << 2);
    const int ch0 = wn * 32 + l15;
#pragma unroll
    for (int ni = 0; ni < 2; ++ni) {
      int ch = ch0 + ni * 16;
      float bias = (ch < 32) ? br[ch] : bi[ch - 32];
#pragma unroll
      for (int mi = 0; mi < 2; ++mi)
#pragma unroll
        for (int j = 0; j < 4; ++j) {
          int row = lrow0 + mi * 16 + j;
          int byteoff =
              row * 128 + ((((ch >> 3) ^ (row & 7)) << 4)) + (ch & 7) * 2;
          *(__hip_bfloat16*)(smem + byteoff) =
              __float2bfloat16(fmaxf(acc[mi][ni][j] + bias, 0.f));
        }
    }
  }
  __syncthreads();
#pragma unroll
  for (int it = 0; it < 2; ++it) {
    int W = it * 8192 + tid * 16;
    int row = W >> 7;
    int slot = (W & 127) >> 4;
    int m = p0 + row;
    if (m < 26244) {
      uint4 v = *(const uint4*)(smem + row * 128 + ((slot ^ (row & 7)) << 4));
      int b = m / 6561, p = m % 6561;
      int d1 = p / 729, r = p % 729;
      int d2 = r / 81;
      r %= 81;
      int d3 = r / 9, d4 = r % 9;
      int q = (((d1 + 1) * 11 + (d2 + 1)) * 11 + (d3 + 1)) * 11 + (d4 + 1);
      *(uint4*)(xp + ((size_t)(b * 14641 + q)) * 64 + slot * 8) = v;
    }
  }
}

// ---- Layer 2: K-split, flat grid 412 with pair-major XCD-chunked swizzle.
//      4 waves 2Mx2N (64x64); BK=64; 2x32KB buffers; bf16 partial store. ----
__global__ __launch_bounds__(256) void cconv2_ksplit(
    const __hip_bfloat16* __restrict__ xp, const __hip_bfloat16* __restrict__ wb,
    __hip_bfloat16* __restrict__ part) {
  __shared__ __align__(128) char smem[65536];  // 2 x (A 16KB | B 16KB)
  const int tid = threadIdx.x;
  const int l = tid & 63, w = tid >> 6;        // 4 waves
  const int wm = w & 1, wn = w >> 1;           // 2M x 2N, wave tile 64x64

  // bijective XCD-chunked pair-major swizzle: nwg=412 = 4*52 + 4*51
  int xcd = blockIdx.x & 7, ii = blockIdx.x >> 3;
  int pid = (xcd < 4) ? xcd * 52 + ii : 208 + (xcd - 4) * 51 + ii;
  const int m0 = (pid >> 1) * 128;
  const int ky = pid & 1;                      // K-half: taps [0,41) / [41,81)

  const int swz = ((l & 7) ^ (l >> 3)) << 4;
  const char* xpB = (const char*)xp;
  const char* wB = (const char*)wb;
  int q00[4], rbB[4];
#pragma unroll
  for (int c = 0; c < 4; ++c) {
    int row = w * 32 + c * 8 + (l >> 3);
    int m = m0 + row;
    if (m > 26243) m = 26243;
    int b = m / 6561, p = m % 6561;
    int d1 = p / 729, r = p % 729;
    int d2 = r / 81;
    r %= 81;
    int d3 = r / 9, d4 = r % 9;
    q00[c] = b * 14641 + ((d1 * 11 + d2) * 11 + d3) * 11 + d4;
    rbB[c] = row * 128 + swz;
  }

  const int l15 = l & 15;
  const int klo = (l >> 4) << 4;
  const int sx = (l & 7) << 4;
  const int arow0 = (wm * 64 + l15) * 128;
  const int brow0 = 16384 + (wn * 64 + l15) * 128;

  f32x4 acc[4][4];
#pragma unroll
  for (int mi = 0; mi < 4; ++mi)
#pragma unroll
    for (int ni = 0; ni < 4; ++ni) acc[mi][ni] = (f32x4){0.f, 0.f, 0.f, 0.f};

  auto stage = [&](int t, int nb) {
    int j1 = t / 27, j2 = (t / 9) % 3, j3 = (t / 3) % 3, j4 = t % 3;
    int delta = ((j1 * 11 + j2) * 11 + j3) * 11 + j4;
#pragma unroll
    for (int c = 0; c < 4; ++c) {
      GLD16(xpB + (((size_t)(q00[c] + delta)) << 7) + swz,
            nb + w * 4096 + c * 1024);
      GLD16(wB + (((size_t)t) << 14) + rbB[c],
            nb + 16384 + w * 4096 + c * 1024);
    }
  };

  const int t0 = ky * 41;            // 0 or 41
  const int nt = 41 - ky;            // 41 or 40

  stage(t0, 0);

  for (int ti = 0; ti < nt; ++ti) {
    asm volatile("s_waitcnt vmcnt(0)" ::: "memory");
    __builtin_amdgcn_s_barrier();
    if (ti + 1 < nt) stage(t0 + ti + 1, ((ti + 1) & 1) * 32768);
    const char* sb = smem + (ti & 1) * 32768;
#pragma unroll
    for (int kh = 0; kh < 2; ++kh) {
      const int kx = ((kh << 6) + klo) ^ sx;
      bf16x8v af[4], bfr[4];
#pragma unroll
      for (int mi = 0; mi < 4; ++mi)
        af[mi] = *(const bf16x8v*)(sb + arow0 + mi * 2048 + kx);
#pragma unroll
      for (int ni = 0; ni < 4; ++ni)
        bfr[ni] = *(const bf16x8v*)(sb + brow0 + ni * 2048 + kx);
#pragma unroll
      for (int mi = 0; mi < 4; ++mi)
#pragma unroll
        for (int ni = 0; ni < 4; ++ni)
          acc[mi][ni] = __builtin_amdgcn_mfma_f32_16x16x32_bf16(
              af[mi], bfr[ni], acc[mi][ni], 0, 0, 0);
    }
  }

  __hip_bfloat16* pp = part + (size_t)ky * 3359232;
  const int prow = m0 + wm * 64 + ((l >> 4) << 2);
  const int col0 = wn * 64 + l15;
#pragma unroll
  for (int ni = 0; ni < 4; ++ni) {
    int cn = col0 + ni * 16;
#pragma unroll
    for (int mi = 0; mi < 4; ++mi)
#pragma unroll
      for (int j = 0; j < 4; ++j) {
        int m = prow + mi * 16 + j;
        if (m < 26244)
          pp[(size_t)m * 128 + cn] = __float2bfloat16(acc[mi][ni][j]);
      }
  }
}

// ---- L3+L4 fused, M=64 tile (48KB LDS -> TLP). 8 waves 1Mx8N. --------------
__global__ __launch_bounds__(512) void gemm_fused34(
    const __hip_bfloat16* __restrict__ p0, const __hip_bfloat16* __restrict__ p1,
    const __hip_bfloat16* __restrict__ w3, const __hip_bfloat16* __restrict__ w4,
    const float* __restrict__ b2r, const float* __restrict__ b2i,
    const float* __restrict__ b3r, const float* __restrict__ b3i,
    const float* __restrict__ b4r, const float* __restrict__ b4i,
    __hip_bfloat16* __restrict__ a4) {
  __shared__ __align__(128) char smem[49152];  // a2 16KB | a3 32KB @16384
  const int tid = threadIdx.x, l = tid & 63, w = tid >> 6;
  const int wn = w;  // 1M x 8N, wave tile 64x32
  const int m0 = blockIdx.x * 64;

  {
    int r = tid >> 3;                // 0..63
    int cb = (tid & 7) * 16;         // 16 ch per thread
    int m = m0 + r;
    if (m > 26243) m = 26243;
    const uint2* q0 = (const uint2*)(p0 + (size_t)m * 128 + cb);
    const uint2* q1 = (const uint2*)(p1 + (size_t)m * 128 + cb);
    __hip_bfloat16 tmp[16];
#pragma unroll
    for (int i = 0; i < 4; ++i) {
      uint2 ua = q0[i], ub = q1[i];
      const __hip_bfloat16* a = (const __hip_bfloat16*)&ua;
      const __hip_bfloat16* b = (const __hip_bfloat16*)&ub;
#pragma unroll
      for (int e = 0; e < 4; ++e) {
        int cn = cb + i * 4 + e;
        float bias = (cn < 64) ? b2r[cn] : b2i[cn - 64];
        float s = __bfloat162float(a[e]) + __bfloat162float(b[e]) + bias;
        tmp[i * 4 + e] = __float2bfloat16(fmaxf(s, 0.f));
      }
    }
    const int rs = (r & 7) << 4;
#pragma unroll
    for (int s4 = 0; s4 < 2; ++s4) {
      int col = cb * 2 + s4 * 16;
      *(uint4*)(smem + r * 256 + (col ^ rs)) = ((const uint4*)tmp)[s4];
    }
  }
  __syncthreads();

  const int l15 = l & 15;
  const int klo = (l >> 4) << 4;
  const int sx = (l & 7) << 4;

  f32x4 acc[4][2];
#pragma unroll
  for (int mi = 0; mi < 4; ++mi)
#pragma unroll
    for (int ni = 0; ni < 2; ++ni) acc[mi][ni] = (f32x4){0.f, 0.f, 0.f, 0.f};

  {
    const int arow3 = l15 * 256;
    const char* b3b = (const char*)w3 + (size_t)(wn * 32 + l15) * 256 + klo;
#pragma unroll
    for (int kh = 0; kh < 4; ++kh) {
      const int kx = ((kh << 6) + klo) ^ sx;
      bf16x8v af[4], bfr[2];
#pragma unroll
      for (int mi = 0; mi < 4; ++mi)
        af[mi] = *(const bf16x8v*)(smem + arow3 + mi * 4096 + kx);
#pragma unroll
      for (int ni = 0; ni < 2; ++ni)
        bfr[ni] = *(const bf16x8v*)(b3b + ni * 4096 + kh * 64);
#pragma unroll
      for (int mi = 0; mi < 4; ++mi)
#pragma unroll
        for (int ni = 0; ni < 2; ++ni)
          acc[mi][ni] = __builtin_amdgcn_mfma_f32_16x16x32_bf16(
              af[mi], bfr[ni], acc[mi][ni], 0, 0, 0);
    }
  }

  {
    const int lrow = (l >> 4) << 2;
    const int col0 = wn * 32 + l15;
#pragma unroll
    for (int ni = 0; ni < 2; ++ni) {
      int cn = col0 + ni * 16;
      float bias = (cn < 128) ? b3r[cn] : b3i[cn - 128];
#pragma unroll
      for (int mi = 0; mi < 4; ++mi) {
        int row = lrow + mi * 16;
#pragma unroll
        for (int j = 0; j < 4; ++j) {
          float v = fmaxf(acc[mi][ni][j] + bias, 0.f);
          int addr = (16384 + (row + j) * 512 + cn * 2) ^ (((row + j) & 7) << 4);
          *(__hip_bfloat16*)(smem + addr) = __float2bfloat16(v);
        }
      }
    }
  }
  __syncthreads();

#pragma unroll
  for (int mi = 0; mi < 4; ++mi)
#pragma unroll
    for (int ni = 0; ni < 2; ++ni) acc[mi][ni] = (f32x4){0.f, 0.f, 0.f, 0.f};
  {
    const int arow4 = 16384 + l15 * 512;
    const char* b4b = (const char*)w4 + (size_t)(wn * 32 + l15) * 512 + klo;
#pragma unroll
    for (int kh = 0; kh < 8; ++kh) {
      const int kx = ((kh << 6) + klo) ^ sx;
      bf16x8v af[4], bfr[2];
#pragma unroll
      for (int mi = 0; mi < 4; ++mi)
        af[mi] = *(const bf16x8v*)(smem + arow4 + mi * 8192 + kx);
#pragma unroll
      for (int ni = 0; ni < 2; ++ni)
        bfr[ni] = *(const bf16x8v*)(b4b + ni * 8192 + kh * 64);
#pragma unroll
      for (int mi = 0; mi < 4; ++mi)
#pragma unroll
        for (int ni = 0; ni < 2; ++ni)
          acc[mi][ni] = __builtin_amdgcn_mfma_f32_16x16x32_bf16(
              af[mi], bfr[ni], acc[mi][ni], 0, 0, 0);
    }
  }

  {
    const int prow = m0 + ((l >> 4) << 2);
    const int col0 = wn * 32 + l15;
#pragma unroll
    for (int ni = 0; ni < 2; ++ni) {
      int cn = col0 + ni * 16;
      float bias = (cn < 128) ? b4r[cn] : b4i[cn - 128];
#pragma unroll
      for (int mi = 0; mi < 4; ++mi)
#pragma unroll
        for (int j = 0; j < 4; ++j) {
          int m = prow + mi * 16 + j;
          if (m < 26244)
            a4[(size_t)m * 256 + cn] =
                __float2bfloat16(fmaxf(acc[mi][ni][j] + bias, 0.f));
        }
    }
  }
}

// ---- L5 GEMM ---------------------------------------------------------------
template <int K, int S2>
__global__ __launch_bounds__(512) void gemm_bg(
    const __hip_bfloat16* __restrict__ A, const __hip_bfloat16* __restrict__ Bm,
    const float* __restrict__ br, const float* __restrict__ bi,
    __hip_bfloat16* __restrict__ C, int M, int N, int Cout) {
  constexpr int ROWB = 2 * K;
  constexpr int NKH = K / 32;
  constexpr int LG = (K == 128) ? 8 : 9;
  __shared__ __align__(128) char smem[128 * ROWB];
  const int tid = threadIdx.x, l = tid & 63, w = tid >> 6;
  const int wm = w & 1, wn = w >> 1;
  const int p0 = blockIdx.x * 128, n0 = blockIdx.y * 128;

  const char* aB = (const char*)A;
#pragma unroll
  for (int g = 0; g < NKH; ++g) {
    int W = (w * NKH + g) * 1024 + (l << 4);
    int row = W >> LG;
    int cb = W & (ROWB - 1);
    int m = p0 + row;
    if (m >= M) m = M - 1;
    int srcrow;
    if (S2) {
      int bb_ = m / 625, r = m % 625;
      int d1 = r / 125;
      r %= 125;
      int d2 = r / 25;
      r %= 25;
      int d3 = r / 5, d4 = r % 5;
      srcrow = bb_ * 6561 + d1 * 1458 + d2 * 162 + d3 * 18 + d4 * 2;
    } else {
      srcrow = m;
    }
    GLD16(aB + (size_t)srcrow * ROWB + (cb ^ ((row & 7) << 4)), W);
  }
  asm volatile("s_waitcnt vmcnt(0)" ::: "memory");
  __syncthreads();

  const int l15 = l & 15;
  const int klo = (l >> 4) << 4;
  const int sx = (l & 7) << 4;
  const int arow0 = (wm * 64 + l15) * ROWB;
  const char* bb = (const char*)Bm + (size_t)(n0 + wn * 32 + l15) * ROWB + klo;

  f32x4 acc[4][2];
#pragma unroll
  for (int mi = 0; mi < 4; ++mi)
#pragma unroll
    for (int ni = 0; ni < 2; ++ni) acc[mi][ni] = (f32x4){0.f, 0.f, 0.f, 0.f};

#pragma unroll
  for (int kh = 0; kh < NKH; ++kh) {
    bf16x8v bfr[2];
#pragma unroll
    for (int ni = 0; ni < 2; ++ni)
      bfr[ni] = *(const bf16x8v*)(bb + ni * 16 * ROWB + kh * 64);
    const int kx = ((kh << 6) + klo) ^ sx;
    bf16x8v af[4];
#pragma unroll
    for (int mi = 0; mi < 4; ++mi)
      af[mi] = *(const bf16x8v*)(smem + arow0 + mi * 16 * ROWB + kx);
#pragma unroll
    for (int mi = 0; mi < 4; ++mi)
#pragma unroll
      for (int ni = 0; ni < 2; ++ni)
        acc[mi][ni] = __builtin_amdgcn_mfma_f32_16x16x32_bf16(
            af[mi], bfr[ni], acc[mi][ni], 0, 0, 0);
  }

  const int prow = p0 + wm * 64 + ((l >> 4) << 2);
  const int col0 = n0 + wn * 32 + l15;
#pragma unroll
  for (int ni = 0; ni < 2; ++ni) {
    int cn = col0 + ni * 16;
    float bias = (cn < Cout) ? br[cn] : bi[cn - Cout];
#pragma unroll
    for (int mi = 0; mi < 4; ++mi)
#pragma unroll
      for (int j = 0; j < 4; ++j) {
        int m = prow + mi * 16 + j;
        if (m < M)
          C[(size_t)m * N + cn] =
              __float2bfloat16(fmaxf(acc[mi][ni][j] + bias, 0.f));
      }
  }
}

// ---- FC --------------------------------------------------------------------
__global__ __launch_bounds__(256) void fc_kernel(
    const __hip_bfloat16* __restrict__ a5, const float* __restrict__ fcw,
    const float* __restrict__ fcb, float* __restrict__ out) {
  int bc = blockIdx.x * 4 + (threadIdx.x >> 6);
  int b = bc >> 6, c = bc & 63;
  int lane = threadIdx.x & 63;
  const __hip_bfloat16* base = a5 + (size_t)b * 625 * 128;
  float sr = 0.f, si = 0.f;
  for (int p = lane; p < 625; p += 64) {
    float wv = fcw[p];
    sr += __bfloat162float(base[(size_t)p * 128 + c]) * wv;
    si += __bfloat162float(base[(size_t)p * 128 + 64 + c]) * wv;
  }
#pragma unroll
  for (int s = 32; s > 0; s >>= 1) {
    sr += __shfl_down(sr, s);
    si += __shfl_down(si, s);
  }
  if (lane == 0) {
    out[bc] = sr + fcb[0];
    out[256 + bc] = si;
  }
}

extern "C" void kernel_launch(void* const* d_in, const int* in_sizes, int n_in,
                              void* d_out, int out_size, void* d_ws,
                              size_t ws_size, hipStream_t stream) {
  const float* xr = (const float*)d_in[0];
  const float* xi = (const float*)d_in[1];
  const float* w1r = (const float*)d_in[2];
  const float* w1i = (const float*)d_in[3];
  const float* b1r = (const float*)d_in[4];
  const float* b1i = (const float*)d_in[5];
  const float* w2r = (const float*)d_in[6];
  const float* w2i = (const float*)d_in[7];
  const float* b2r = (const float*)d_in[8];
  const float* b2i = (const float*)d_in[9];
  const float* w3r = (const float*)d_in[10];
  const float* w3i = (const float*)d_in[11];
  const float* b3r = (const float*)d_in[12];
  const float* b3i = (const float*)d_in[13];
  const float* w4r = (const float*)d_in[14];
  const float* w4i = (const float*)d_in[15];
  const float* b4r = (const float*)d_in[16];
  const float* b4i = (const float*)d_in[17];
  const float* w5r = (const float*)d_in[18];
  const float* w5i = (const float*)d_in[19];
  const float* b5r = (const float*)d_in[20];
  const float* b5i = (const float*)d_in[21];
  const float* fcw = (const float*)d_in[22];
  const float* fcb = (const float*)d_in[23];
  float* out = (float*)d_out;

  float* ws = (float*)d_ws;
  __hip_bfloat16* wt2b = (__hip_bfloat16*)(ws + 5184);     // 663552 bf16
  __hip_bfloat16* w3b = (__hip_bfloat16*)(ws + 336960);    // 32768 bf16
  __hip_bfloat16* w4b = (__hip_bfloat16*)(ws + 353344);    // 65536 bf16
  __hip_bfloat16* w5b = (__hip_bfloat16*)(ws + 386112);    // 32768 bf16
  __hip_bfloat16* xp = (__hip_bfloat16*)(ws + 402496);     // 3748096 bf16
  __hip_bfloat16* a4 = (__hip_bfloat16*)(ws + 3956160);    // 6718464 bf16
  __hip_bfloat16* a5 = (__hip_bfloat16*)(ws + 7315392);    // 320000 bf16
  __hip_bfloat16* w1b = (__hip_bfloat16*)(ws + 7475392);   // 16384 bf16
  // part: dedicated (fused34 reads it while writing a4)
  __hip_bfloat16* part = (__hip_bfloat16*)(ws + 7483584);  // 6718464 bf16
  // Aim aliases a4 region (dead until fused34; tail overruns into a5,
  // which is rewritten later by gemm_bg)
  __hip_bfloat16* Aim = (__hip_bfloat16*)(ws + 3956160);

  prep_fused<<<dim3(5410), 256, 0, stream>>>(
      xr, xi, w1r, w1i, w2r, w2i, w3r, w3i, w4r, w4i, w5r, w5i, w1b, wt2b,
      w3b, w4b, w5b, (uint4*)xp, Aim);

  gemm_l1<<<dim3(206), 512, 0, stream>>>(Aim, w1b, b1r, b1i, xp);
  cconv2_ksplit<<<dim3(412), 256, 0, stream>>>(xp, wt2b, part);
  gemm_fused34<<<dim3(411), 512, 0, stream>>>(
      part, part + 3359232, w3b, w4b, b2r, b2i, b3r, b3i, b4r, b4i, a4);
  gemm_bg<256, 1><<<dim3(20, 1), 512, 0, stream>>>(a4, w5b, b5r, b5i, a5,
                                                   2500, 128, 64);
  fc_kernel<<<dim3(64), 256, 0, stream>>>(a5, fcw, fcb, out);
}